// Round 1
// baseline (809.613 us; speedup 1.0000x reference)
//
#include <hip/hip_runtime.h>
#include <cstdio>

#define NTOK 8192
#define DIM 1024
#define HID 2048
#define NE 8
#define NPAIR (NTOK * 2)

typedef __attribute__((ext_vector_type(8))) short bf16x8;
typedef __attribute__((ext_vector_type(4))) float f32x4;

typedef const __attribute__((address_space(1))) void* gas_ptr;
typedef __attribute__((address_space(3))) void* las_ptr;

__device__ __forceinline__ void async16(const void* g, void* s) {
  // direct global->LDS, 16B per lane; LDS dest = wave-uniform base + lane*16
  __builtin_amdgcn_global_load_lds((gas_ptr)g, (las_ptr)s, 16, 0, 0);
}

__device__ __forceinline__ unsigned short f2bf(float f) {
  unsigned int u = __float_as_uint(f);
  u = (u + 0x7fff + ((u >> 16) & 1)) >> 16;  // RNE
  return (unsigned short)u;
}

__device__ __forceinline__ float bf2f(unsigned short u) {
  return __uint_as_float((unsigned int)u << 16);
}

// GEMM LDS tiles are [row][64 bf16] = 128B rows. Physical 16B-chunk of (row r,
// logical chunk c) is c ^ (r&7) -> fragment reads spread across all 8 bank
// groups (2-way aliasing only, free on gfx950). Staging lane loads global
// chunk (slot&7)^(row&7) since its LDS slot chunk is fixed.
// All GEMMs: 128x128 tile, BK=64, 2x2 waves, single 4x4 f32x4 acc per wave.
// r6: double-buffered LDS + prefetch-next-before-compute + ONE barrier per
// K-step (T3-minimum). Old structure (stage -> sync(drain) -> compute -> sync)
// exposed full L2/HBM latency per K-step at ~1.6 blocks/CU effective
// occupancy -> MfmaUtil 15%. Prefetch hides load latency under MFMA.

// ---------------------------------------------------------------------------
// prep: w1[e][d][h] -> w1bt[e][h][d] (bf16), w2 same, w3[e][h][d] -> w3bt[e][d][h]
// ---------------------------------------------------------------------------
__global__ __launch_bounds__(256) void prep_kernel(
    const float* __restrict__ w1, const float* __restrict__ w2,
    const float* __restrict__ w3, unsigned short* __restrict__ w1bt,
    unsigned short* __restrict__ w2bt, unsigned short* __restrict__ w3bt) {
  const int z = blockIdx.y;
  const int m = z >> 3, e = z & 7;
  int R, C;
  const float* in;
  unsigned short* outp;
  if (m == 0)      { R = DIM; C = HID; in = w1; outp = w1bt; }
  else if (m == 1) { R = DIM; C = HID; in = w2; outp = w2bt; }
  else             { R = HID; C = DIM; in = w3; outp = w3bt; }
  in += (size_t)e * DIM * HID;
  outp += (size_t)e * DIM * HID;

  const int tilesx = C >> 5;
  const int c0 = (blockIdx.x % tilesx) * 32;
  const int r0 = (blockIdx.x / tilesx) * 32;

  __shared__ float tile[32][33];
  const int c = threadIdx.x & 31, rr = threadIdx.x >> 5;
#pragma unroll
  for (int i = 0; i < 4; i++) {
    const int r = rr + i * 8;
    tile[r][c] = in[(size_t)(r0 + r) * C + c0 + c];
  }
  __syncthreads();
#pragma unroll
  for (int i = 0; i < 4; i++) {
    const int cc2 = rr + i * 8;  // column of original = row of output
    outp[(size_t)(c0 + cc2) * R + r0 + c] = f2bf(tile[c][cc2]);
  }
}

// ---------------------------------------------------------------------------
// gating: 1 wave per token. Transposed gate_w in LDS -> conflict-free b128
// reads. No atomics here (counts in finalize).
// ---------------------------------------------------------------------------
__global__ __launch_bounds__(256) void gate_kernel(
    const float* __restrict__ x, const float* __restrict__ gw,
    const float* __restrict__ gb, unsigned short* __restrict__ xb,
    float* __restrict__ scores, int* __restrict__ route_e,
    float* __restrict__ route_w) {
  __shared__ float sgwT[NE][DIM];  // 32 KB, transposed [e][d]
  const int tid = threadIdx.x;
#pragma unroll
  for (int i = 0; i < 8; i++) {
    const int j = i * 256 + tid;               // float4 index into gw[DIM][NE]
    const float4 v = ((const float4*)gw)[j];
    const int d = j >> 1, e0 = (j & 1) * 4;    // 2-way bank alias on store: free
    sgwT[e0 + 0][d] = v.x; sgwT[e0 + 1][d] = v.y;
    sgwT[e0 + 2][d] = v.z; sgwT[e0 + 3][d] = v.w;
  }
  __syncthreads();

  const int wv = tid >> 6, lane = tid & 63;
  const int t = blockIdx.x * 4 + wv;
  float acc[NE] = {0.f, 0.f, 0.f, 0.f, 0.f, 0.f, 0.f, 0.f};
  const float4* x4 = (const float4*)(x + (size_t)t * DIM);
#pragma unroll
  for (int i = 0; i < 4; i++) {
    const float4 xv = x4[i * 64 + lane];
    const int d4 = i * 64 + lane;              // float4 index; byte addr lane*16
    ushort4 xbv;
    xbv.x = f2bf(xv.x); xbv.y = f2bf(xv.y);
    xbv.z = f2bf(xv.z); xbv.w = f2bf(xv.w);
    *(ushort4*)(xb + (size_t)t * DIM + d4 * 4) = xbv;
#pragma unroll
    for (int e = 0; e < NE; e++) {
      const float4 wv4 = *(const float4*)&sgwT[e][d4 * 4];  // ds_read_b128, no conflict
      acc[e] += xv.x * wv4.x + xv.y * wv4.y + xv.z * wv4.z + xv.w * wv4.w;
    }
  }
#pragma unroll
  for (int e = 0; e < NE; e++)
#pragma unroll
    for (int s = 32; s; s >>= 1) acc[e] += __shfl_xor(acc[e], s, 64);

  if (lane == 0) {
    float l[NE], m = -1e30f;
#pragma unroll
    for (int e = 0; e < NE; e++) { l[e] = acc[e] + gb[e]; m = fmaxf(m, l[e]); }
    float p[NE], sum = 0.f;
#pragma unroll
    for (int e = 0; e < NE; e++) { p[e] = __expf(l[e] - m); sum += p[e]; }
    const float inv = 1.f / sum;
    float s[NE];
#pragma unroll
    for (int e = 0; e < NE; e++) { s[e] = p[e] * inv; scores[t * NE + e] = s[e]; }
    int i1 = 0;
    for (int e = 1; e < NE; e++) if (s[e] > s[i1]) i1 = e;
    int i2 = -1;
    for (int e = 0; e < NE; e++) {
      if (e == i1) continue;
      if (i2 < 0 || s[e] > s[i2]) i2 = e;
    }
    route_e[t * 2] = i1; route_e[t * 2 + 1] = i2;
    route_w[t * 2] = s[i1]; route_w[t * 2 + 1] = s[i2];
  }
}

// ---------------------------------------------------------------------------
// finalize: usage -> lb_loss (d_out tail); counts via route_e histogram;
// prefix offsets; cursors. Writes every ctrl field (no memset needed).
// ---------------------------------------------------------------------------
__global__ void finalize_kernel(const float* __restrict__ scores,
                                const int* __restrict__ route_e,
                                int* __restrict__ ctrl,
                                float* __restrict__ out_lb) {
  __shared__ float red[1024];
  __shared__ int hist[NE];
  const int tid = threadIdx.x;
  if (tid < NE) hist[tid] = 0;
  const int e = tid & 7, row = tid >> 3;
  float s = 0.f;
  for (int i = 0; i < 64; i++) s += scores[(size_t)(row + i * 128) * NE + e];
  red[tid] = s;
  __syncthreads();  // hist zero + red visible
#pragma unroll
  for (int i = 0; i < 16; i++)
    atomicAdd(&hist[route_e[i * 1024 + tid]], 1);
  for (int st = 512; st >= 8; st >>= 1) {
    __syncthreads();
    if (tid < st) red[tid] += red[tid + st];
  }
  __syncthreads();
  if (tid == 0) {
    float lb = 0.f;
    for (int ee = 0; ee < NE; ee++) {
      const float u = red[ee] * (1.f / 8192.f);
      lb -= u * __logf(u + 1e-9f);
    }
    *out_lb = lb;
    int o = 0;
    for (int ee = 0; ee < NE; ee++) {
      ctrl[ee] = hist[ee];    // counts
      ctrl[8 + ee] = o;       // offsets
      ctrl[17 + ee] = o;      // cursors
      o += hist[ee];
    }
    ctrl[16] = o;
  }
}

// ---------------------------------------------------------------------------
// scatter: build per-expert compacted token lists + inverse map pair_pos
// ---------------------------------------------------------------------------
__global__ void scatter_kernel(const int* __restrict__ route_e,
                               const float* __restrict__ route_w,
                               int* __restrict__ ctrl,
                               int* __restrict__ tok_list,
                               float* __restrict__ pair_w,
                               int* __restrict__ pair_pos) {
  const int t = blockIdx.x * 256 + threadIdx.x;
  if (t >= NTOK) return;
#pragma unroll
  for (int k = 0; k < 2; k++) {
    const int e = route_e[t * 2 + k];
    const int p = atomicAdd(&ctrl[17 + e], 1);
    tok_list[p] = t;
    pair_w[p] = route_w[t * 2 + k] * 0.70710678118654752f;  // comb * 1/sqrt(2)
    pair_pos[t * 2 + k] = p;
  }
}

// ---------------------------------------------------------------------------
// stage1a: h = X@W1 + b1 for routed rows -> act (bf16)
// grid (16, 64, 8), block 256. 128x128 tile, BK=64, 2x2 waves, single acc.
// Double-buffered LDS, prefetch t+1 before compute t, one barrier per step.
// ---------------------------------------------------------------------------
__global__ __launch_bounds__(256) void stage1a_kernel(
    const unsigned short* __restrict__ xb, const unsigned short* __restrict__ wbt,
    const float* __restrict__ b1, const int* __restrict__ tok_list,
    const int* __restrict__ ctrl, unsigned short* __restrict__ act) {
  const int e = blockIdx.z;
  const int cnt = ctrl[e];
  const int ytile = blockIdx.y;
  if (ytile * 128 >= cnt) return;
  const int off = ctrl[8 + e];
  const int rows = min(128, cnt - ytile * 128);
  const int h0 = blockIdx.x * 128;

  __shared__ unsigned short sX[2][128 * 64];
  __shared__ unsigned short sW[2][128 * 64];
  __shared__ int stok[128];

  const int tid = threadIdx.x;
  const int wv = tid >> 6, lane = tid & 63;

  if (tid < 128) stok[tid] = tok_list[off + ytile * 128 + min(tid, rows - 1)];
  __syncthreads();

  const int rr = tid >> 3;
  const int c8 = ((tid & 7) ^ (rr & 7)) * 8;  // swizzled chunk offset (shorts)
  const unsigned short* wp = wbt + (size_t)e * HID * DIM + (size_t)h0 * DIM;
  const unsigned short* gx[4];
  const unsigned short* gw[4];
#pragma unroll
  for (int r = 0; r < 4; r++) {
    gx[r] = xb + (size_t)stok[rr + r * 32] * DIM + c8;
    gw[r] = wp + (size_t)(rr + r * 32) * DIM + c8;
  }

  f32x4 acc[4][4];
#pragma unroll
  for (int i = 0; i < 4; i++)
#pragma unroll
    for (int j = 0; j < 4; j++) acc[i][j] = (f32x4){0.f, 0.f, 0.f, 0.f};

  const int wr = wv >> 1, wc = wv & 1;
  const int l15 = lane & 15, q = lane >> 4, r7 = lane & 7;

  // prologue: stage K-step 0 into buf0
#pragma unroll
  for (int r = 0; r < 4; r++) {
    async16(gx[r], sX[0] + (r * 256 + wv * 64) * 8);
    async16(gw[r], sW[0] + (r * 256 + wv * 64) * 8);
    gx[r] += 64; gw[r] += 64;
  }
  __syncthreads();

  const int NT = DIM / 64;
  for (int t = 0; t < NT; t++) {
    const int cur = t & 1;
    if (t + 1 < NT) {
#pragma unroll
      for (int r = 0; r < 4; r++) {
        async16(gx[r], sX[cur ^ 1] + (r * 256 + wv * 64) * 8);
        async16(gw[r], sW[cur ^ 1] + (r * 256 + wv * 64) * 8);
        gx[r] += 64; gw[r] += 64;
      }
    }
#pragma unroll
    for (int kk = 0; kk < 2; kk++) {
      const int pch = ((kk * 4 + q) ^ r7) * 8;
      bf16x8 af[4], bf[4];
#pragma unroll
      for (int i = 0; i < 4; i++)
        af[i] = *(const bf16x8*)(sX[cur] + (wr * 64 + i * 16 + l15) * 64 + pch);
#pragma unroll
      for (int j = 0; j < 4; j++)
        bf[j] = *(const bf16x8*)(sW[cur] + (wc * 64 + j * 16 + l15) * 64 + pch);
#pragma unroll
      for (int i = 0; i < 4; i++)
#pragma unroll
        for (int j = 0; j < 4; j++)
          acc[i][j] =
              __builtin_amdgcn_mfma_f32_16x16x32_bf16(af[i], bf[j], acc[i][j], 0, 0, 0);
    }
    __syncthreads();
  }

#pragma unroll
  for (int i = 0; i < 4; i++)
#pragma unroll
    for (int j = 0; j < 4; j++) {
      const int hcol = h0 + wc * 64 + j * 16 + l15;
      const float bb = b1[e * HID + hcol];
#pragma unroll
      for (int rg = 0; rg < 4; rg++) {
        const int row = wr * 64 + i * 16 + q * 4 + rg;
        if (row < rows)
          act[(size_t)(off + ytile * 128 + row) * HID + hcol] = f2bf(acc[i][j][rg] + bb);
      }
    }
}

// ---------------------------------------------------------------------------
// stage1b: g = X@W2 + b2; act *= in-place: act = h * silu(g)
// ---------------------------------------------------------------------------
__global__ __launch_bounds__(256) void stage1b_kernel(
    const unsigned short* __restrict__ xb, const unsigned short* __restrict__ wbt,
    const float* __restrict__ b2, const int* __restrict__ tok_list,
    const int* __restrict__ ctrl, unsigned short* __restrict__ act) {
  const int e = blockIdx.z;
  const int cnt = ctrl[e];
  const int ytile = blockIdx.y;
  if (ytile * 128 >= cnt) return;
  const int off = ctrl[8 + e];
  const int rows = min(128, cnt - ytile * 128);
  const int h0 = blockIdx.x * 128;

  __shared__ unsigned short sX[2][128 * 64];
  __shared__ unsigned short sW[2][128 * 64];
  __shared__ int stok[128];

  const int tid = threadIdx.x;
  const int wv = tid >> 6, lane = tid & 63;

  if (tid < 128) stok[tid] = tok_list[off + ytile * 128 + min(tid, rows - 1)];
  __syncthreads();

  const int rr = tid >> 3;
  const int c8 = ((tid & 7) ^ (rr & 7)) * 8;
  const unsigned short* wp = wbt + (size_t)e * HID * DIM + (size_t)h0 * DIM;
  const unsigned short* gx[4];
  const unsigned short* gw[4];
#pragma unroll
  for (int r = 0; r < 4; r++) {
    gx[r] = xb + (size_t)stok[rr + r * 32] * DIM + c8;
    gw[r] = wp + (size_t)(rr + r * 32) * DIM + c8;
  }

  f32x4 acc[4][4];
#pragma unroll
  for (int i = 0; i < 4; i++)
#pragma unroll
    for (int j = 0; j < 4; j++) acc[i][j] = (f32x4){0.f, 0.f, 0.f, 0.f};

  const int wr = wv >> 1, wc = wv & 1;
  const int l15 = lane & 15, q = lane >> 4, r7 = lane & 7;

#pragma unroll
  for (int r = 0; r < 4; r++) {
    async16(gx[r], sX[0] + (r * 256 + wv * 64) * 8);
    async16(gw[r], sW[0] + (r * 256 + wv * 64) * 8);
    gx[r] += 64; gw[r] += 64;
  }
  __syncthreads();

  const int NT = DIM / 64;
  for (int t = 0; t < NT; t++) {
    const int cur = t & 1;
    if (t + 1 < NT) {
#pragma unroll
      for (int r = 0; r < 4; r++) {
        async16(gx[r], sX[cur ^ 1] + (r * 256 + wv * 64) * 8);
        async16(gw[r], sW[cur ^ 1] + (r * 256 + wv * 64) * 8);
        gx[r] += 64; gw[r] += 64;
      }
    }
#pragma unroll
    for (int kk = 0; kk < 2; kk++) {
      const int pch = ((kk * 4 + q) ^ r7) * 8;
      bf16x8 af[4], bf[4];
#pragma unroll
      for (int i = 0; i < 4; i++)
        af[i] = *(const bf16x8*)(sX[cur] + (wr * 64 + i * 16 + l15) * 64 + pch);
#pragma unroll
      for (int j = 0; j < 4; j++)
        bf[j] = *(const bf16x8*)(sW[cur] + (wc * 64 + j * 16 + l15) * 64 + pch);
#pragma unroll
      for (int i = 0; i < 4; i++)
#pragma unroll
        for (int j = 0; j < 4; j++)
          acc[i][j] =
              __builtin_amdgcn_mfma_f32_16x16x32_bf16(af[i], bf[j], acc[i][j], 0, 0, 0);
    }
    __syncthreads();
  }

#pragma unroll
  for (int i = 0; i < 4; i++)
#pragma unroll
    for (int j = 0; j < 4; j++) {
      const int hcol = h0 + wc * 64 + j * 16 + l15;
      const float bb = b2[e * HID + hcol];
#pragma unroll
      for (int rg = 0; rg < 4; rg++) {
        const int row = wr * 64 + i * 16 + q * 4 + rg;
        if (row < rows) {
          const size_t idx = (size_t)(off + ytile * 128 + row) * HID + hcol;
          const float g = acc[i][j][rg] + bb;
          const float h = bf2f(act[idx]);
          act[idx] = f2bf(h * (g / (1.f + __expf(-g))));
        }
      }
    }
}

// ---------------------------------------------------------------------------
// stage2 (store path): pair_out[pr] = (act @ W3 + b3) * wt  (bf16)
// grid (8, 64, 8), block 256. K = HID.
// ---------------------------------------------------------------------------
__global__ __launch_bounds__(256) void stage2s_kernel(
    const unsigned short* __restrict__ act, const unsigned short* __restrict__ w3bt,
    const float* __restrict__ b3, const float* __restrict__ pair_w,
    const int* __restrict__ ctrl, unsigned short* __restrict__ pair_out) {
  const int e = blockIdx.z;
  const int cnt = ctrl[e];
  const int ytile = blockIdx.y;
  if (ytile * 128 >= cnt) return;
  const int off = ctrl[8 + e];
  const int rows = min(128, cnt - ytile * 128);
  const int d0 = blockIdx.x * 128;
  const int rbase = off + ytile * 128;

  __shared__ unsigned short sA[2][128 * 64];
  __shared__ unsigned short sW[2][128 * 64];

  const int tid = threadIdx.x;
  const int wv = tid >> 6, lane = tid & 63;
  const int rr = tid >> 3;
  const int c8 = ((tid & 7) ^ (rr & 7)) * 8;
  const unsigned short* w3p = w3bt + (size_t)e * DIM * HID + (size_t)d0 * HID;
  const unsigned short* ga[4];
  const unsigned short* gw[4];
#pragma unroll
  for (int r = 0; r < 4; r++) {
    ga[r] = act + (size_t)(rbase + min(rr + r * 32, rows - 1)) * HID + c8;
    gw[r] = w3p + (size_t)(rr + r * 32) * HID + c8;
  }

  f32x4 acc[4][4];
#pragma unroll
  for (int i = 0; i < 4; i++)
#pragma unroll
    for (int j = 0; j < 4; j++) acc[i][j] = (f32x4){0.f, 0.f, 0.f, 0.f};

  const int wr = wv >> 1, wc = wv & 1;
  const int l15 = lane & 15, q = lane >> 4, r7 = lane & 7;

#pragma unroll
  for (int r = 0; r < 4; r++) {
    async16(ga[r], sA[0] + (r * 256 + wv * 64) * 8);
    async16(gw[r], sW[0] + (r * 256 + wv * 64) * 8);
    ga[r] += 64; gw[r] += 64;
  }
  __syncthreads();

  const int NT = HID / 64;
  for (int t = 0; t < NT; t++) {
    const int cur = t & 1;
    if (t + 1 < NT) {
#pragma unroll
      for (int r = 0; r < 4; r++) {
        async16(ga[r], sA[cur ^ 1] + (r * 256 + wv * 64) * 8);
        async16(gw[r], sW[cur ^ 1] + (r * 256 + wv * 64) * 8);
        ga[r] += 64; gw[r] += 64;
      }
    }
#pragma unroll
    for (int kk = 0; kk < 2; kk++) {
      const int pch = ((kk * 4 + q) ^ r7) * 8;
      bf16x8 af[4], bf[4];
#pragma unroll
      for (int i = 0; i < 4; i++)
        af[i] = *(const bf16x8*)(sA[cur] + (wr * 64 + i * 16 + l15) * 64 + pch);
#pragma unroll
      for (int j = 0; j < 4; j++)
        bf[j] = *(const bf16x8*)(sW[cur] + (wc * 64 + j * 16 + l15) * 64 + pch);
#pragma unroll
      for (int i = 0; i < 4; i++)
#pragma unroll
        for (int j = 0; j < 4; j++)
          acc[i][j] =
              __builtin_amdgcn_mfma_f32_16x16x32_bf16(af[i], bf[j], acc[i][j], 0, 0, 0);
    }
    __syncthreads();
  }

#pragma unroll
  for (int i = 0; i < 4; i++)
#pragma unroll
    for (int rg = 0; rg < 4; rg++) {
      const int row = wr * 64 + i * 16 + q * 4 + rg;
      if (row < rows) {
        const int pr = rbase + row;
        const float wt = pair_w[pr];
#pragma unroll
        for (int j = 0; j < 4; j++) {
          const int dcol = d0 + wc * 64 + j * 16 + l15;
          pair_out[(size_t)pr * DIM + dcol] = f2bf((acc[i][j][rg] + b3[e * DIM + dcol]) * wt);
        }
      }
    }
}

// ---------------------------------------------------------------------------
// stage2 (atomic fallback): out[tok] += (act @ W3 + b3) * wt
// ---------------------------------------------------------------------------
__global__ __launch_bounds__(256) void stage2a_kernel(
    const unsigned short* __restrict__ act, const unsigned short* __restrict__ w3bt,
    const float* __restrict__ b3, const int* __restrict__ tok_list,
    const float* __restrict__ pair_w, const int* __restrict__ ctrl,
    float* __restrict__ out) {
  const int e = blockIdx.z;
  const int cnt = ctrl[e];
  const int ytile = blockIdx.y;
  if (ytile * 128 >= cnt) return;
  const int off = ctrl[8 + e];
  const int rows = min(128, cnt - ytile * 128);
  const int d0 = blockIdx.x * 128;
  const int rbase = off + ytile * 128;

  __shared__ unsigned short sA[2][128 * 64];
  __shared__ unsigned short sW[2][128 * 64];

  const int tid = threadIdx.x;
  const int wv = tid >> 6, lane = tid & 63;
  const int rr = tid >> 3;
  const int c8 = ((tid & 7) ^ (rr & 7)) * 8;
  const unsigned short* w3p = w3bt + (size_t)e * DIM * HID + (size_t)d0 * HID;
  const unsigned short* ga[4];
  const unsigned short* gw[4];
#pragma unroll
  for (int r = 0; r < 4; r++) {
    ga[r] = act + (size_t)(rbase + min(rr + r * 32, rows - 1)) * HID + c8;
    gw[r] = w3p + (size_t)(rr + r * 32) * HID + c8;
  }

  f32x4 acc[4][4];
#pragma unroll
  for (int i = 0; i < 4; i++)
#pragma unroll
    for (int j = 0; j < 4; j++) acc[i][j] = (f32x4){0.f, 0.f, 0.f, 0.f};

  const int wr = wv >> 1, wc = wv & 1;
  const int l15 = lane & 15, q = lane >> 4, r7 = lane & 7;

#pragma unroll
  for (int r = 0; r < 4; r++) {
    async16(ga[r], sA[0] + (r * 256 + wv * 64) * 8);
    async16(gw[r], sW[0] + (r * 256 + wv * 64) * 8);
    ga[r] += 64; gw[r] += 64;
  }
  __syncthreads();

  const int NT = HID / 64;
  for (int t = 0; t < NT; t++) {
    const int cur = t & 1;
    if (t + 1 < NT) {
#pragma unroll
      for (int r = 0; r < 4; r++) {
        async16(ga[r], sA[cur ^ 1] + (r * 256 + wv * 64) * 8);
        async16(gw[r], sW[cur ^ 1] + (r * 256 + wv * 64) * 8);
        ga[r] += 64; gw[r] += 64;
      }
    }
#pragma unroll
    for (int kk = 0; kk < 2; kk++) {
      const int pch = ((kk * 4 + q) ^ r7) * 8;
      bf16x8 af[4], bf[4];
#pragma unroll
      for (int i = 0; i < 4; i++)
        af[i] = *(const bf16x8*)(sA[cur] + (wr * 64 + i * 16 + l15) * 64 + pch);
#pragma unroll
      for (int j = 0; j < 4; j++)
        bf[j] = *(const bf16x8*)(sW[cur] + (wc * 64 + j * 16 + l15) * 64 + pch);
#pragma unroll
      for (int i = 0; i < 4; i++)
#pragma unroll
        for (int j = 0; j < 4; j++)
          acc[i][j] =
              __builtin_amdgcn_mfma_f32_16x16x32_bf16(af[i], bf[j], acc[i][j], 0, 0, 0);
    }
    __syncthreads();
  }

#pragma unroll
  for (int i = 0; i < 4; i++)
#pragma unroll
    for (int rg = 0; rg < 4; rg++) {
      const int row = wr * 64 + i * 16 + q * 4 + rg;
      if (row < rows) {
        const int pr = rbase + row;
        const int tok = tok_list[pr];
        const float wt = pair_w[pr];
#pragma unroll
        for (int j = 0; j < 4; j++) {
          const int dcol = d0 + wc * 64 + j * 16 + l15;
          atomicAdd(out + (size_t)tok * DIM + dcol, (acc[i][j][rg] + b3[e * DIM + dcol]) * wt);
        }
      }
    }
}

// ---------------------------------------------------------------------------
// combine: out[t] = pair_out[pos(t,0)] + pair_out[pos(t,1)]. grid NTOK x 256.
// ---------------------------------------------------------------------------
__global__ __launch_bounds__(256) void combine_kernel(
    const unsigned short* __restrict__ pair_out, const int* __restrict__ pair_pos,
    float* __restrict__ out) {
  const int t = blockIdx.x;
  const int d = threadIdx.x * 4;
  const int p0 = pair_pos[t * 2], p1 = pair_pos[t * 2 + 1];
  const ushort4 a = *(const ushort4*)(pair_out + (size_t)p0 * DIM + d);
  const ushort4 b = *(const ushort4*)(pair_out + (size_t)p1 * DIM + d);
  float4 r;
  r.x = bf2f(a.x) + bf2f(b.x);
  r.y = bf2f(a.y) + bf2f(b.y);
  r.z = bf2f(a.z) + bf2f(b.z);
  r.w = bf2f(a.w) + bf2f(b.w);
  *(float4*)(out + (size_t)t * DIM + d) = r;
}

// ---------------------------------------------------------------------------
// workspace layout (bytes)
// ---------------------------------------------------------------------------
static const size_t SZ_XB  = (size_t)NTOK * DIM * 2;        // 16 MB
static const size_t SZ_W   = (size_t)NE * DIM * HID * 2;    // 32 MB each
static const size_t SZ_ACT = (size_t)NPAIR * HID * 2;       // 64 MB
static const size_t OFF_XB  = 0;
static const size_t OFF_W1  = OFF_XB + SZ_XB;
static const size_t OFF_W2  = OFF_W1 + SZ_W;
static const size_t OFF_W3  = OFF_W2 + SZ_W;
static const size_t OFF_ACT = OFF_W3 + SZ_W;
static const size_t OFF_SC  = OFF_ACT + SZ_ACT;
static const size_t OFF_RE  = OFF_SC + (size_t)NTOK * NE * 4;
static const size_t OFF_RW  = OFF_RE + (size_t)NPAIR * 4;
static const size_t OFF_TL  = OFF_RW + (size_t)NPAIR * 4;
static const size_t OFF_PW  = OFF_TL + (size_t)NPAIR * 4;
static const size_t OFF_PP  = OFF_PW + (size_t)NPAIR * 4;
static const size_t OFF_CT  = OFF_PP + (size_t)NPAIR * 4;
static const size_t WS_BASE = OFF_CT + 128;
static const size_t OFF_PO  = WS_BASE;                      // pair_out bf16, 32 MB
static const size_t WS_FULL = OFF_PO + (size_t)NPAIR * DIM * 2;

extern "C" void kernel_launch(void* const* d_in, const int* in_sizes, int n_in,
                              void* d_out, int out_size, void* d_ws, size_t ws_size,
                              hipStream_t stream) {
  const float* x      = (const float*)d_in[0];
  const float* gate_w = (const float*)d_in[1];
  const float* gate_b = (const float*)d_in[2];
  const float* w1     = (const float*)d_in[3];
  const float* b1     = (const float*)d_in[4];
  const float* w2     = (const float*)d_in[5];
  const float* b2     = (const float*)d_in[6];
  const float* w3     = (const float*)d_in[7];
  const float* b3     = (const float*)d_in[8];
  float* out = (float*)d_out;

  if (ws_size < WS_BASE) {
    fprintf(stderr, "kernel_launch: ws_size %zu < needed %zu\n", ws_size, WS_BASE);
    return;
  }
  const bool store_path = (ws_size >= WS_FULL);

  char* ws = (char*)d_ws;
  unsigned short* xb   = (unsigned short*)(ws + OFF_XB);
  unsigned short* w1bt = (unsigned short*)(ws + OFF_W1);
  unsigned short* w2bt = (unsigned short*)(ws + OFF_W2);
  unsigned short* w3bt = (unsigned short*)(ws + OFF_W3);
  unsigned short* act  = (unsigned short*)(ws + OFF_ACT);
  float* scores        = (float*)(ws + OFF_SC);
  int* route_e         = (int*)(ws + OFF_RE);
  float* route_w       = (float*)(ws + OFF_RW);
  int* tok_list        = (int*)(ws + OFF_TL);
  float* pair_w        = (float*)(ws + OFF_PW);
  int* pair_pos        = (int*)(ws + OFF_PP);
  int* ctrl            = (int*)(ws + OFF_CT);
  unsigned short* pout = (unsigned short*)(ws + OFF_PO);

  if (!store_path)
    hipMemsetAsync(d_out, 0, (size_t)out_size * sizeof(float), stream);

  prep_kernel<<<dim3(2048, 24), 256, 0, stream>>>(w1, w2, w3, w1bt, w2bt, w3bt);
  gate_kernel<<<2048, 256, 0, stream>>>(x, gate_w, gate_b, xb, scores, route_e,
                                        route_w);
  finalize_kernel<<<1, 1024, 0, stream>>>(scores, route_e, ctrl, out + (out_size - 1));
  scatter_kernel<<<32, 256, 0, stream>>>(route_e, route_w, ctrl, tok_list, pair_w,
                                         pair_pos);
  stage1a_kernel<<<dim3(16, 64, 8), 256, 0, stream>>>(xb, w1bt, b1, tok_list, ctrl, act);
  stage1b_kernel<<<dim3(16, 64, 8), 256, 0, stream>>>(xb, w2bt, b2, tok_list, ctrl, act);
  if (store_path) {
    stage2s_kernel<<<dim3(8, 64, 8), 256, 0, stream>>>(act, w3bt, b3, pair_w, ctrl, pout);
    combine_kernel<<<NTOK, 256, 0, stream>>>(pout, pair_pos, out);
  } else {
    stage2a_kernel<<<dim3(8, 64, 8), 256, 0, stream>>>(act, w3bt, b3, tok_list,
                                                       pair_w, ctrl, out);
  }
}

// Round 2
// 809.398 us; speedup vs baseline: 1.0003x; 1.0003x over previous
//
#include <hip/hip_runtime.h>
#include <cstdio>

#define NTOK 8192
#define DIM 1024
#define HID 2048
#define NE 8
#define NPAIR (NTOK * 2)

typedef __attribute__((ext_vector_type(8))) short bf16x8;
typedef __attribute__((ext_vector_type(4))) float f32x4;

typedef const __attribute__((address_space(1))) void* gas_ptr;
typedef __attribute__((address_space(3))) void* las_ptr;

__device__ __forceinline__ void async16(const void* g, void* s) {
  // direct global->LDS, 16B per lane; LDS dest = wave-uniform base + lane*16
  __builtin_amdgcn_global_load_lds((gas_ptr)g, (las_ptr)s, 16, 0, 0);
}

__device__ __forceinline__ unsigned short f2bf(float f) {
  unsigned int u = __float_as_uint(f);
  u = (u + 0x7fff + ((u >> 16) & 1)) >> 16;  // RNE
  return (unsigned short)u;
}

__device__ __forceinline__ float bf2f(unsigned short u) {
  return __uint_as_float((unsigned int)u << 16);
}

// r7: 256x256 tile migration (m248/m230 measured: grouped-GEMM @K=1024
// 2-phase 256^2 = 655 TF vs 128^2 = ~344 TF which we matched exactly).
// 8 waves (512 thr), wave grid 2x4, per-wave 128x64 out = acc[8][4] f32x4.
// LDS 128KB: sX/sW [2][256x64] bf16 dbuf. Same minimum-2-phase loop
// (stage next -> compute cur -> __syncthreads) — no sync-structure change.
// LDS tiles are [row][64 bf16] = 128B rows; physical 16B-chunk of (row r,
// logical chunk c) is c ^ (r&7) -> all fragment reads spread across 8 bank
// groups (2-way aliasing only, free). Staging lane loads global chunk
// (tid&7)^(row&7) since its LDS slot chunk is fixed (gload_lds linear dest).

// ---------------------------------------------------------------------------
// prep: w1[e][d][h] -> w1bt[e][h][d] (bf16), w2 same, w3[e][h][d] -> w3bt[e][d][h]
// ---------------------------------------------------------------------------
__global__ __launch_bounds__(256) void prep_kernel(
    const float* __restrict__ w1, const float* __restrict__ w2,
    const float* __restrict__ w3, unsigned short* __restrict__ w1bt,
    unsigned short* __restrict__ w2bt, unsigned short* __restrict__ w3bt) {
  const int z = blockIdx.y;
  const int m = z >> 3, e = z & 7;
  int R, C;
  const float* in;
  unsigned short* outp;
  if (m == 0)      { R = DIM; C = HID; in = w1; outp = w1bt; }
  else if (m == 1) { R = DIM; C = HID; in = w2; outp = w2bt; }
  else             { R = HID; C = DIM; in = w3; outp = w3bt; }
  in += (size_t)e * DIM * HID;
  outp += (size_t)e * DIM * HID;

  const int tilesx = C >> 5;
  const int c0 = (blockIdx.x % tilesx) * 32;
  const int r0 = (blockIdx.x / tilesx) * 32;

  __shared__ float tile[32][33];
  const int c = threadIdx.x & 31, rr = threadIdx.x >> 5;
#pragma unroll
  for (int i = 0; i < 4; i++) {
    const int r = rr + i * 8;
    tile[r][c] = in[(size_t)(r0 + r) * C + c0 + c];
  }
  __syncthreads();
#pragma unroll
  for (int i = 0; i < 4; i++) {
    const int cc2 = rr + i * 8;  // column of original = row of output
    outp[(size_t)(c0 + cc2) * R + r0 + c] = f2bf(tile[c][cc2]);
  }
}

// ---------------------------------------------------------------------------
// gating: 1 wave per token. Transposed gate_w in LDS -> conflict-free b128
// reads. No atomics here (counts in finalize).
// ---------------------------------------------------------------------------
__global__ __launch_bounds__(256) void gate_kernel(
    const float* __restrict__ x, const float* __restrict__ gw,
    const float* __restrict__ gb, unsigned short* __restrict__ xb,
    float* __restrict__ scores, int* __restrict__ route_e,
    float* __restrict__ route_w) {
  __shared__ float sgwT[NE][DIM];  // 32 KB, transposed [e][d]
  const int tid = threadIdx.x;
#pragma unroll
  for (int i = 0; i < 8; i++) {
    const int j = i * 256 + tid;               // float4 index into gw[DIM][NE]
    const float4 v = ((const float4*)gw)[j];
    const int d = j >> 1, e0 = (j & 1) * 4;    // 2-way bank alias on store: free
    sgwT[e0 + 0][d] = v.x; sgwT[e0 + 1][d] = v.y;
    sgwT[e0 + 2][d] = v.z; sgwT[e0 + 3][d] = v.w;
  }
  __syncthreads();

  const int wv = tid >> 6, lane = tid & 63;
  const int t = blockIdx.x * 4 + wv;
  float acc[NE] = {0.f, 0.f, 0.f, 0.f, 0.f, 0.f, 0.f, 0.f};
  const float4* x4 = (const float4*)(x + (size_t)t * DIM);
#pragma unroll
  for (int i = 0; i < 4; i++) {
    const float4 xv = x4[i * 64 + lane];
    const int d4 = i * 64 + lane;              // float4 index; byte addr lane*16
    ushort4 xbv;
    xbv.x = f2bf(xv.x); xbv.y = f2bf(xv.y);
    xbv.z = f2bf(xv.z); xbv.w = f2bf(xv.w);
    *(ushort4*)(xb + (size_t)t * DIM + d4 * 4) = xbv;
#pragma unroll
    for (int e = 0; e < NE; e++) {
      const float4 wv4 = *(const float4*)&sgwT[e][d4 * 4];  // ds_read_b128, no conflict
      acc[e] += xv.x * wv4.x + xv.y * wv4.y + xv.z * wv4.z + xv.w * wv4.w;
    }
  }
#pragma unroll
  for (int e = 0; e < NE; e++)
#pragma unroll
    for (int s = 32; s; s >>= 1) acc[e] += __shfl_xor(acc[e], s, 64);

  if (lane == 0) {
    float l[NE], m = -1e30f;
#pragma unroll
    for (int e = 0; e < NE; e++) { l[e] = acc[e] + gb[e]; m = fmaxf(m, l[e]); }
    float p[NE], sum = 0.f;
#pragma unroll
    for (int e = 0; e < NE; e++) { p[e] = __expf(l[e] - m); sum += p[e]; }
    const float inv = 1.f / sum;
    float s[NE];
#pragma unroll
    for (int e = 0; e < NE; e++) { s[e] = p[e] * inv; scores[t * NE + e] = s[e]; }
    int i1 = 0;
    for (int e = 1; e < NE; e++) if (s[e] > s[i1]) i1 = e;
    int i2 = -1;
    for (int e = 0; e < NE; e++) {
      if (e == i1) continue;
      if (i2 < 0 || s[e] > s[i2]) i2 = e;
    }
    route_e[t * 2] = i1; route_e[t * 2 + 1] = i2;
    route_w[t * 2] = s[i1]; route_w[t * 2 + 1] = s[i2];
  }
}

// ---------------------------------------------------------------------------
// finalize: usage -> lb_loss (d_out tail); counts via route_e histogram;
// prefix offsets; cursors. Writes every ctrl field (no memset needed).
// ---------------------------------------------------------------------------
__global__ void finalize_kernel(const float* __restrict__ scores,
                                const int* __restrict__ route_e,
                                int* __restrict__ ctrl,
                                float* __restrict__ out_lb) {
  __shared__ float red[1024];
  __shared__ int hist[NE];
  const int tid = threadIdx.x;
  if (tid < NE) hist[tid] = 0;
  const int e = tid & 7, row = tid >> 3;
  float s = 0.f;
  for (int i = 0; i < 64; i++) s += scores[(size_t)(row + i * 128) * NE + e];
  red[tid] = s;
  __syncthreads();  // hist zero + red visible
#pragma unroll
  for (int i = 0; i < 16; i++)
    atomicAdd(&hist[route_e[i * 1024 + tid]], 1);
  for (int st = 512; st >= 8; st >>= 1) {
    __syncthreads();
    if (tid < st) red[tid] += red[tid + st];
  }
  __syncthreads();
  if (tid == 0) {
    float lb = 0.f;
    for (int ee = 0; ee < NE; ee++) {
      const float u = red[ee] * (1.f / 8192.f);
      lb -= u * __logf(u + 1e-9f);
    }
    *out_lb = lb;
    int o = 0;
    for (int ee = 0; ee < NE; ee++) {
      ctrl[ee] = hist[ee];    // counts
      ctrl[8 + ee] = o;       // offsets
      ctrl[17 + ee] = o;      // cursors
      o += hist[ee];
    }
    ctrl[16] = o;
  }
}

// ---------------------------------------------------------------------------
// scatter: build per-expert compacted token lists + inverse map pair_pos
// ---------------------------------------------------------------------------
__global__ void scatter_kernel(const int* __restrict__ route_e,
                               const float* __restrict__ route_w,
                               int* __restrict__ ctrl,
                               int* __restrict__ tok_list,
                               float* __restrict__ pair_w,
                               int* __restrict__ pair_pos) {
  const int t = blockIdx.x * 256 + threadIdx.x;
  if (t >= NTOK) return;
#pragma unroll
  for (int k = 0; k < 2; k++) {
    const int e = route_e[t * 2 + k];
    const int p = atomicAdd(&ctrl[17 + e], 1);
    tok_list[p] = t;
    pair_w[p] = route_w[t * 2 + k] * 0.70710678118654752f;  // comb * 1/sqrt(2)
    pair_pos[t * 2 + k] = p;
  }
}

// ---------------------------------------------------------------------------
// stage1a: h = X@W1 + b1 for routed rows -> act (bf16)
// grid (8, 64, 8), block 512. 256x256 tile, BK=64, 2x4 waves, acc[8][4].
// ---------------------------------------------------------------------------
__global__ __launch_bounds__(512) void stage1a_kernel(
    const unsigned short* __restrict__ xb, const unsigned short* __restrict__ wbt,
    const float* __restrict__ b1, const int* __restrict__ tok_list,
    const int* __restrict__ ctrl, unsigned short* __restrict__ act) {
  const int e = blockIdx.z;
  const int cnt = ctrl[e];
  const int ytile = blockIdx.y;
  if (ytile * 256 >= cnt) return;
  const int off = ctrl[8 + e];
  const int rows = min(256, cnt - ytile * 256);
  const int h0 = blockIdx.x * 256;

  __shared__ unsigned short sX[2][256 * 64];
  __shared__ unsigned short sW[2][256 * 64];

  const int tid = threadIdx.x;
  const int wv = tid >> 6, lane = tid & 63;
  const int rr = tid >> 3;
  const int c8 = ((tid & 7) ^ (rr & 7)) * 8;  // swizzled chunk offset (shorts)

  const unsigned short* wp = wbt + (size_t)e * HID * DIM + (size_t)h0 * DIM;
  const unsigned short* gx[4];
  const unsigned short* gw[4];
#pragma unroll
  for (int r = 0; r < 4; r++) {
    const int row = rr + r * 64;
    gx[r] = xb + (size_t)tok_list[off + ytile * 256 + min(row, rows - 1)] * DIM + c8;
    gw[r] = wp + (size_t)row * DIM + c8;
  }

  f32x4 acc[8][4];
#pragma unroll
  for (int i = 0; i < 8; i++)
#pragma unroll
    for (int j = 0; j < 4; j++) acc[i][j] = (f32x4){0.f, 0.f, 0.f, 0.f};

  const int wr = wv >> 2, wc = wv & 3;
  const int l15 = lane & 15, q = lane >> 4, r7 = lane & 7;

  // prologue: stage K-tile 0 into buf0
#pragma unroll
  for (int r = 0; r < 4; r++) {
    async16(gx[r], sX[0] + (r * 512 + wv * 64) * 8);
    async16(gw[r], sW[0] + (r * 512 + wv * 64) * 8);
    gx[r] += 64; gw[r] += 64;
  }
  __syncthreads();

  const int NT = DIM / 64;
  for (int t = 0; t < NT; t++) {
    const int cur = t & 1;
    if (t + 1 < NT) {
#pragma unroll
      for (int r = 0; r < 4; r++) {
        async16(gx[r], sX[cur ^ 1] + (r * 512 + wv * 64) * 8);
        async16(gw[r], sW[cur ^ 1] + (r * 512 + wv * 64) * 8);
        gx[r] += 64; gw[r] += 64;
      }
    }
#pragma unroll
    for (int kk = 0; kk < 2; kk++) {
      const int pch = ((kk * 4 + q) ^ r7) * 8;
      bf16x8 af[8], bf[4];
#pragma unroll
      for (int i = 0; i < 8; i++)
        af[i] = *(const bf16x8*)(sX[cur] + (wr * 128 + i * 16 + l15) * 64 + pch);
#pragma unroll
      for (int j = 0; j < 4; j++)
        bf[j] = *(const bf16x8*)(sW[cur] + (wc * 64 + j * 16 + l15) * 64 + pch);
#pragma unroll
      for (int i = 0; i < 8; i++)
#pragma unroll
        for (int j = 0; j < 4; j++)
          acc[i][j] =
              __builtin_amdgcn_mfma_f32_16x16x32_bf16(af[i], bf[j], acc[i][j], 0, 0, 0);
    }
    __syncthreads();
  }

#pragma unroll
  for (int i = 0; i < 8; i++)
#pragma unroll
    for (int j = 0; j < 4; j++) {
      const int hcol = h0 + wc * 64 + j * 16 + l15;
      const float bb = b1[e * HID + hcol];
#pragma unroll
      for (int rg = 0; rg < 4; rg++) {
        const int row = wr * 128 + i * 16 + q * 4 + rg;
        if (row < rows)
          act[(size_t)(off + ytile * 256 + row) * HID + hcol] = f2bf(acc[i][j][rg] + bb);
      }
    }
}

// ---------------------------------------------------------------------------
// stage1b: g = X@W2 + b2; act *= in-place: act = h * silu(g)
// ---------------------------------------------------------------------------
__global__ __launch_bounds__(512) void stage1b_kernel(
    const unsigned short* __restrict__ xb, const unsigned short* __restrict__ wbt,
    const float* __restrict__ b2, const int* __restrict__ tok_list,
    const int* __restrict__ ctrl, unsigned short* __restrict__ act) {
  const int e = blockIdx.z;
  const int cnt = ctrl[e];
  const int ytile = blockIdx.y;
  if (ytile * 256 >= cnt) return;
  const int off = ctrl[8 + e];
  const int rows = min(256, cnt - ytile * 256);
  const int h0 = blockIdx.x * 256;

  __shared__ unsigned short sX[2][256 * 64];
  __shared__ unsigned short sW[2][256 * 64];

  const int tid = threadIdx.x;
  const int wv = tid >> 6, lane = tid & 63;
  const int rr = tid >> 3;
  const int c8 = ((tid & 7) ^ (rr & 7)) * 8;

  const unsigned short* wp = wbt + (size_t)e * HID * DIM + (size_t)h0 * DIM;
  const unsigned short* gx[4];
  const unsigned short* gw[4];
#pragma unroll
  for (int r = 0; r < 4; r++) {
    const int row = rr + r * 64;
    gx[r] = xb + (size_t)tok_list[off + ytile * 256 + min(row, rows - 1)] * DIM + c8;
    gw[r] = wp + (size_t)row * DIM + c8;
  }

  f32x4 acc[8][4];
#pragma unroll
  for (int i = 0; i < 8; i++)
#pragma unroll
    for (int j = 0; j < 4; j++) acc[i][j] = (f32x4){0.f, 0.f, 0.f, 0.f};

  const int wr = wv >> 2, wc = wv & 3;
  const int l15 = lane & 15, q = lane >> 4, r7 = lane & 7;

#pragma unroll
  for (int r = 0; r < 4; r++) {
    async16(gx[r], sX[0] + (r * 512 + wv * 64) * 8);
    async16(gw[r], sW[0] + (r * 512 + wv * 64) * 8);
    gx[r] += 64; gw[r] += 64;
  }
  __syncthreads();

  const int NT = DIM / 64;
  for (int t = 0; t < NT; t++) {
    const int cur = t & 1;
    if (t + 1 < NT) {
#pragma unroll
      for (int r = 0; r < 4; r++) {
        async16(gx[r], sX[cur ^ 1] + (r * 512 + wv * 64) * 8);
        async16(gw[r], sW[cur ^ 1] + (r * 512 + wv * 64) * 8);
        gx[r] += 64; gw[r] += 64;
      }
    }
#pragma unroll
    for (int kk = 0; kk < 2; kk++) {
      const int pch = ((kk * 4 + q) ^ r7) * 8;
      bf16x8 af[8], bf[4];
#pragma unroll
      for (int i = 0; i < 8; i++)
        af[i] = *(const bf16x8*)(sX[cur] + (wr * 128 + i * 16 + l15) * 64 + pch);
#pragma unroll
      for (int j = 0; j < 4; j++)
        bf[j] = *(const bf16x8*)(sW[cur] + (wc * 64 + j * 16 + l15) * 64 + pch);
#pragma unroll
      for (int i = 0; i < 8; i++)
#pragma unroll
        for (int j = 0; j < 4; j++)
          acc[i][j] =
              __builtin_amdgcn_mfma_f32_16x16x32_bf16(af[i], bf[j], acc[i][j], 0, 0, 0);
    }
    __syncthreads();
  }

#pragma unroll
  for (int i = 0; i < 8; i++)
#pragma unroll
    for (int j = 0; j < 4; j++) {
      const int hcol = h0 + wc * 64 + j * 16 + l15;
      const float bb = b2[e * HID + hcol];
#pragma unroll
      for (int rg = 0; rg < 4; rg++) {
        const int row = wr * 128 + i * 16 + q * 4 + rg;
        if (row < rows) {
          const size_t idx = (size_t)(off + ytile * 256 + row) * HID + hcol;
          const float g = acc[i][j][rg] + bb;
          const float h = bf2f(act[idx]);
          act[idx] = f2bf(h * (g / (1.f + __expf(-g))));
        }
      }
    }
}

// ---------------------------------------------------------------------------
// stage2 (store path): pair_out[pr] = (act @ W3 + b3) * wt  (bf16)
// grid (4, 64, 8), block 512. K = HID.
// ---------------------------------------------------------------------------
__global__ __launch_bounds__(512) void stage2s_kernel(
    const unsigned short* __restrict__ act, const unsigned short* __restrict__ w3bt,
    const float* __restrict__ b3, const float* __restrict__ pair_w,
    const int* __restrict__ ctrl, unsigned short* __restrict__ pair_out) {
  const int e = blockIdx.z;
  const int cnt = ctrl[e];
  const int ytile = blockIdx.y;
  if (ytile * 256 >= cnt) return;
  const int off = ctrl[8 + e];
  const int rows = min(256, cnt - ytile * 256);
  const int d0 = blockIdx.x * 256;
  const int rbase = off + ytile * 256;

  __shared__ unsigned short sA[2][256 * 64];
  __shared__ unsigned short sW[2][256 * 64];

  const int tid = threadIdx.x;
  const int wv = tid >> 6, lane = tid & 63;
  const int rr = tid >> 3;
  const int c8 = ((tid & 7) ^ (rr & 7)) * 8;
  const unsigned short* w3p = w3bt + (size_t)e * DIM * HID + (size_t)d0 * HID;
  const unsigned short* ga[4];
  const unsigned short* gw[4];
#pragma unroll
  for (int r = 0; r < 4; r++) {
    const int row = rr + r * 64;
    ga[r] = act + (size_t)(rbase + min(row, rows - 1)) * HID + c8;
    gw[r] = w3p + (size_t)row * HID + c8;
  }

  f32x4 acc[8][4];
#pragma unroll
  for (int i = 0; i < 8; i++)
#pragma unroll
    for (int j = 0; j < 4; j++) acc[i][j] = (f32x4){0.f, 0.f, 0.f, 0.f};

  const int wr = wv >> 2, wc = wv & 3;
  const int l15 = lane & 15, q = lane >> 4, r7 = lane & 7;

#pragma unroll
  for (int r = 0; r < 4; r++) {
    async16(ga[r], sA[0] + (r * 512 + wv * 64) * 8);
    async16(gw[r], sW[0] + (r * 512 + wv * 64) * 8);
    ga[r] += 64; gw[r] += 64;
  }
  __syncthreads();

  const int NT = HID / 64;
  for (int t = 0; t < NT; t++) {
    const int cur = t & 1;
    if (t + 1 < NT) {
#pragma unroll
      for (int r = 0; r < 4; r++) {
        async16(ga[r], sA[cur ^ 1] + (r * 512 + wv * 64) * 8);
        async16(gw[r], sW[cur ^ 1] + (r * 512 + wv * 64) * 8);
        ga[r] += 64; gw[r] += 64;
      }
    }
#pragma unroll
    for (int kk = 0; kk < 2; kk++) {
      const int pch = ((kk * 4 + q) ^ r7) * 8;
      bf16x8 af[8], bf[4];
#pragma unroll
      for (int i = 0; i < 8; i++)
        af[i] = *(const bf16x8*)(sA[cur] + (wr * 128 + i * 16 + l15) * 64 + pch);
#pragma unroll
      for (int j = 0; j < 4; j++)
        bf[j] = *(const bf16x8*)(sW[cur] + (wc * 64 + j * 16 + l15) * 64 + pch);
#pragma unroll
      for (int i = 0; i < 8; i++)
#pragma unroll
        for (int j = 0; j < 4; j++)
          acc[i][j] =
              __builtin_amdgcn_mfma_f32_16x16x32_bf16(af[i], bf[j], acc[i][j], 0, 0, 0);
    }
    __syncthreads();
  }

#pragma unroll
  for (int i = 0; i < 8; i++)
#pragma unroll
    for (int rg = 0; rg < 4; rg++) {
      const int row = wr * 128 + i * 16 + q * 4 + rg;
      if (row < rows) {
        const int pr = rbase + row;
        const float wt = pair_w[pr];
#pragma unroll
        for (int j = 0; j < 4; j++) {
          const int dcol = d0 + wc * 64 + j * 16 + l15;
          pair_out[(size_t)pr * DIM + dcol] = f2bf((acc[i][j][rg] + b3[e * DIM + dcol]) * wt);
        }
      }
    }
}

// ---------------------------------------------------------------------------
// stage2 (atomic fallback): out[tok] += (act @ W3 + b3) * wt
// ---------------------------------------------------------------------------
__global__ __launch_bounds__(512) void stage2a_kernel(
    const unsigned short* __restrict__ act, const unsigned short* __restrict__ w3bt,
    const float* __restrict__ b3, const int* __restrict__ tok_list,
    const float* __restrict__ pair_w, const int* __restrict__ ctrl,
    float* __restrict__ out) {
  const int e = blockIdx.z;
  const int cnt = ctrl[e];
  const int ytile = blockIdx.y;
  if (ytile * 256 >= cnt) return;
  const int off = ctrl[8 + e];
  const int rows = min(256, cnt - ytile * 256);
  const int d0 = blockIdx.x * 256;
  const int rbase = off + ytile * 256;

  __shared__ unsigned short sA[2][256 * 64];
  __shared__ unsigned short sW[2][256 * 64];

  const int tid = threadIdx.x;
  const int wv = tid >> 6, lane = tid & 63;
  const int rr = tid >> 3;
  const int c8 = ((tid & 7) ^ (rr & 7)) * 8;
  const unsigned short* w3p = w3bt + (size_t)e * DIM * HID + (size_t)d0 * HID;
  const unsigned short* ga[4];
  const unsigned short* gw[4];
#pragma unroll
  for (int r = 0; r < 4; r++) {
    const int row = rr + r * 64;
    ga[r] = act + (size_t)(rbase + min(row, rows - 1)) * HID + c8;
    gw[r] = w3p + (size_t)row * HID + c8;
  }

  f32x4 acc[8][4];
#pragma unroll
  for (int i = 0; i < 8; i++)
#pragma unroll
    for (int j = 0; j < 4; j++) acc[i][j] = (f32x4){0.f, 0.f, 0.f, 0.f};

  const int wr = wv >> 2, wc = wv & 3;
  const int l15 = lane & 15, q = lane >> 4, r7 = lane & 7;

#pragma unroll
  for (int r = 0; r < 4; r++) {
    async16(ga[r], sA[0] + (r * 512 + wv * 64) * 8);
    async16(gw[r], sW[0] + (r * 512 + wv * 64) * 8);
    ga[r] += 64; gw[r] += 64;
  }
  __syncthreads();

  const int NT = HID / 64;
  for (int t = 0; t < NT; t++) {
    const int cur = t & 1;
    if (t + 1 < NT) {
#pragma unroll
      for (int r = 0; r < 4; r++) {
        async16(ga[r], sA[cur ^ 1] + (r * 512 + wv * 64) * 8);
        async16(gw[r], sW[cur ^ 1] + (r * 512 + wv * 64) * 8);
        ga[r] += 64; gw[r] += 64;
      }
    }
#pragma unroll
    for (int kk = 0; kk < 2; kk++) {
      const int pch = ((kk * 4 + q) ^ r7) * 8;
      bf16x8 af[8], bf[4];
#pragma unroll
      for (int i = 0; i < 8; i++)
        af[i] = *(const bf16x8*)(sA[cur] + (wr * 128 + i * 16 + l15) * 64 + pch);
#pragma unroll
      for (int j = 0; j < 4; j++)
        bf[j] = *(const bf16x8*)(sW[cur] + (wc * 64 + j * 16 + l15) * 64 + pch);
#pragma unroll
      for (int i = 0; i < 8; i++)
#pragma unroll
        for (int j = 0; j < 4; j++)
          acc[i][j] =
              __builtin_amdgcn_mfma_f32_16x16x32_bf16(af[i], bf[j], acc[i][j], 0, 0, 0);
    }
    __syncthreads();
  }

#pragma unroll
  for (int i = 0; i < 8; i++)
#pragma unroll
    for (int rg = 0; rg < 4; rg++) {
      const int row = wr * 128 + i * 16 + q * 4 + rg;
      if (row < rows) {
        const int pr = rbase + row;
        const int tok = tok_list[pr];
        const float wt = pair_w[pr];
#pragma unroll
        for (int j = 0; j < 4; j++) {
          const int dcol = d0 + wc * 64 + j * 16 + l15;
          atomicAdd(out + (size_t)tok * DIM + dcol, (acc[i][j][rg] + b3[e * DIM + dcol]) * wt);
        }
      }
    }
}

// ---------------------------------------------------------------------------
// combine: out[t] = pair_out[pos(t,0)] + pair_out[pos(t,1)]. grid NTOK x 256.
// ---------------------------------------------------------------------------
__global__ __launch_bounds__(256) void combine_kernel(
    const unsigned short* __restrict__ pair_out, const int* __restrict__ pair_pos,
    float* __restrict__ out) {
  const int t = blockIdx.x;
  const int d = threadIdx.x * 4;
  const int p0 = pair_pos[t * 2], p1 = pair_pos[t * 2 + 1];
  const ushort4 a = *(const ushort4*)(pair_out + (size_t)p0 * DIM + d);
  const ushort4 b = *(const ushort4*)(pair_out + (size_t)p1 * DIM + d);
  float4 r;
  r.x = bf2f(a.x) + bf2f(b.x);
  r.y = bf2f(a.y) + bf2f(b.y);
  r.z = bf2f(a.z) + bf2f(b.z);
  r.w = bf2f(a.w) + bf2f(b.w);
  *(float4*)(out + (size_t)t * DIM + d) = r;
}

// ---------------------------------------------------------------------------
// workspace layout (bytes)
// ---------------------------------------------------------------------------
static const size_t SZ_XB  = (size_t)NTOK * DIM * 2;        // 16 MB
static const size_t SZ_W   = (size_t)NE * DIM * HID * 2;    // 32 MB each
static const size_t SZ_ACT = (size_t)NPAIR * HID * 2;       // 64 MB
static const size_t OFF_XB  = 0;
static const size_t OFF_W1  = OFF_XB + SZ_XB;
static const size_t OFF_W2  = OFF_W1 + SZ_W;
static const size_t OFF_W3  = OFF_W2 + SZ_W;
static const size_t OFF_ACT = OFF_W3 + SZ_W;
static const size_t OFF_SC  = OFF_ACT + SZ_ACT;
static const size_t OFF_RE  = OFF_SC + (size_t)NTOK * NE * 4;
static const size_t OFF_RW  = OFF_RE + (size_t)NPAIR * 4;
static const size_t OFF_TL  = OFF_RW + (size_t)NPAIR * 4;
static const size_t OFF_PW  = OFF_TL + (size_t)NPAIR * 4;
static const size_t OFF_PP  = OFF_PW + (size_t)NPAIR * 4;
static const size_t OFF_CT  = OFF_PP + (size_t)NPAIR * 4;
static const size_t WS_BASE = OFF_CT + 128;
static const size_t OFF_PO  = WS_BASE;                      // pair_out bf16, 32 MB
static const size_t WS_FULL = OFF_PO + (size_t)NPAIR * DIM * 2;

extern "C" void kernel_launch(void* const* d_in, const int* in_sizes, int n_in,
                              void* d_out, int out_size, void* d_ws, size_t ws_size,
                              hipStream_t stream) {
  const float* x      = (const float*)d_in[0];
  const float* gate_w = (const float*)d_in[1];
  const float* gate_b = (const float*)d_in[2];
  const float* w1     = (const float*)d_in[3];
  const float* b1     = (const float*)d_in[4];
  const float* w2     = (const float*)d_in[5];
  const float* b2     = (const float*)d_in[6];
  const float* w3     = (const float*)d_in[7];
  const float* b3     = (const float*)d_in[8];
  float* out = (float*)d_out;

  if (ws_size < WS_BASE) {
    fprintf(stderr, "kernel_launch: ws_size %zu < needed %zu\n", ws_size, WS_BASE);
    return;
  }
  const bool store_path = (ws_size >= WS_FULL);

  char* ws = (char*)d_ws;
  unsigned short* xb   = (unsigned short*)(ws + OFF_XB);
  unsigned short* w1bt = (unsigned short*)(ws + OFF_W1);
  unsigned short* w2bt = (unsigned short*)(ws + OFF_W2);
  unsigned short* w3bt = (unsigned short*)(ws + OFF_W3);
  unsigned short* act  = (unsigned short*)(ws + OFF_ACT);
  float* scores        = (float*)(ws + OFF_SC);
  int* route_e         = (int*)(ws + OFF_RE);
  float* route_w       = (float*)(ws + OFF_RW);
  int* tok_list        = (int*)(ws + OFF_TL);
  float* pair_w        = (float*)(ws + OFF_PW);
  int* pair_pos        = (int*)(ws + OFF_PP);
  int* ctrl            = (int*)(ws + OFF_CT);
  unsigned short* pout = (unsigned short*)(ws + OFF_PO);

  if (!store_path)
    hipMemsetAsync(d_out, 0, (size_t)out_size * sizeof(float), stream);

  prep_kernel<<<dim3(2048, 24), 256, 0, stream>>>(w1, w2, w3, w1bt, w2bt, w3bt);
  gate_kernel<<<2048, 256, 0, stream>>>(x, gate_w, gate_b, xb, scores, route_e,
                                        route_w);
  finalize_kernel<<<1, 1024, 0, stream>>>(scores, route_e, ctrl, out + (out_size - 1));
  scatter_kernel<<<32, 256, 0, stream>>>(route_e, route_w, ctrl, tok_list, pair_w,
                                         pair_pos);
  stage1a_kernel<<<dim3(8, 64, 8), 512, 0, stream>>>(xb, w1bt, b1, tok_list, ctrl, act);
  stage1b_kernel<<<dim3(8, 64, 8), 512, 0, stream>>>(xb, w2bt, b2, tok_list, ctrl, act);
  if (store_path) {
    stage2s_kernel<<<dim3(4, 64, 8), 512, 0, stream>>>(act, w3bt, b3, pair_w, ctrl, pout);
    combine_kernel<<<NTOK, 256, 0, stream>>>(pout, pair_pos, out);
  } else {
    stage2a_kernel<<<dim3(4, 64, 8), 512, 0, stream>>>(act, w3bt, b3, tok_list,
                                                       pair_w, ctrl, out);
  }
}

// Round 3
// 659.756 us; speedup vs baseline: 1.2271x; 1.2268x over previous
//
#include <hip/hip_runtime.h>
#include <cstdio>

#define NTOK 8192
#define DIM 1024
#define HID 2048
#define NE 8
#define NPAIR (NTOK * 2)

typedef __attribute__((ext_vector_type(8))) short bf16x8;
typedef __attribute__((ext_vector_type(4))) float f32x4;

typedef const __attribute__((address_space(1))) void* gas_ptr;
typedef __attribute__((address_space(3))) void* las_ptr;

__device__ __forceinline__ void async16(const void* g, void* s) {
  // direct global->LDS, 16B per lane; LDS dest = wave-uniform base + lane*16
  __builtin_amdgcn_global_load_lds((gas_ptr)g, (las_ptr)s, 16, 0, 0);
}

__device__ __forceinline__ unsigned short f2bf(float f) {
  unsigned int u = __float_as_uint(f);
  u = (u + 0x7fff + ((u >> 16) & 1)) >> 16;  // RNE
  return (unsigned short)u;
}

__device__ __forceinline__ float bf2f(unsigned short u) {
  return __uint_as_float((unsigned int)u << 16);
}

// r8: FUSED stage1. Evidence: all GEMM variants run at hbm_bytes / ~1.2 TB/s
// (r0 248MB/1.29 = 192us; r2 240MB/1.15 = 208us) -> effective-BW-bound, not
// latency-bound. So cut bytes: fuse W1/W2 passes (X staged once, no 128 MB
// h round-trip through act). Swapped-operand MFMA (A=W, B=X) puts 4
// consecutive hcols in each lane's acc -> ushort4 (8B) stores, q-groups
// merge to 32B segments; one f32x4 bias load per j.
// LDS tiles are [row][64 bf16] = 128B rows; physical 16B-chunk of (row r,
// logical chunk c) is c ^ (r&7); staging lane loads global chunk
// (tid&7)^(row&7) since its LDS slot chunk is fixed (gload_lds linear dest).

// ---------------------------------------------------------------------------
// prep: w1[e][d][h] -> w1bt[e][h][d] (bf16), w2 same, w3[e][h][d] -> w3bt[e][d][h]
// ---------------------------------------------------------------------------
__global__ __launch_bounds__(256) void prep_kernel(
    const float* __restrict__ w1, const float* __restrict__ w2,
    const float* __restrict__ w3, unsigned short* __restrict__ w1bt,
    unsigned short* __restrict__ w2bt, unsigned short* __restrict__ w3bt) {
  const int z = blockIdx.y;
  const int m = z >> 3, e = z & 7;
  int R, C;
  const float* in;
  unsigned short* outp;
  if (m == 0)      { R = DIM; C = HID; in = w1; outp = w1bt; }
  else if (m == 1) { R = DIM; C = HID; in = w2; outp = w2bt; }
  else             { R = HID; C = DIM; in = w3; outp = w3bt; }
  in += (size_t)e * DIM * HID;
  outp += (size_t)e * DIM * HID;

  const int tilesx = C >> 5;
  const int c0 = (blockIdx.x % tilesx) * 32;
  const int r0 = (blockIdx.x / tilesx) * 32;

  __shared__ float tile[32][33];
  const int c = threadIdx.x & 31, rr = threadIdx.x >> 5;
#pragma unroll
  for (int i = 0; i < 4; i++) {
    const int r = rr + i * 8;
    tile[r][c] = in[(size_t)(r0 + r) * C + c0 + c];
  }
  __syncthreads();
#pragma unroll
  for (int i = 0; i < 4; i++) {
    const int cc2 = rr + i * 8;  // column of original = row of output
    outp[(size_t)(c0 + cc2) * R + r0 + c] = f2bf(tile[c][cc2]);
  }
}

// ---------------------------------------------------------------------------
// gating: 1 wave per token. Transposed gate_w in LDS -> conflict-free b128
// reads. No atomics here (counts in finalize).
// ---------------------------------------------------------------------------
__global__ __launch_bounds__(256) void gate_kernel(
    const float* __restrict__ x, const float* __restrict__ gw,
    const float* __restrict__ gb, unsigned short* __restrict__ xb,
    float* __restrict__ scores, int* __restrict__ route_e,
    float* __restrict__ route_w) {
  __shared__ float sgwT[NE][DIM];  // 32 KB, transposed [e][d]
  const int tid = threadIdx.x;
#pragma unroll
  for (int i = 0; i < 8; i++) {
    const int j = i * 256 + tid;               // float4 index into gw[DIM][NE]
    const float4 v = ((const float4*)gw)[j];
    const int d = j >> 1, e0 = (j & 1) * 4;    // 2-way bank alias on store: free
    sgwT[e0 + 0][d] = v.x; sgwT[e0 + 1][d] = v.y;
    sgwT[e0 + 2][d] = v.z; sgwT[e0 + 3][d] = v.w;
  }
  __syncthreads();

  const int wv = tid >> 6, lane = tid & 63;
  const int t = blockIdx.x * 4 + wv;
  float acc[NE] = {0.f, 0.f, 0.f, 0.f, 0.f, 0.f, 0.f, 0.f};
  const float4* x4 = (const float4*)(x + (size_t)t * DIM);
#pragma unroll
  for (int i = 0; i < 4; i++) {
    const float4 xv = x4[i * 64 + lane];
    const int d4 = i * 64 + lane;              // float4 index; byte addr lane*16
    ushort4 xbv;
    xbv.x = f2bf(xv.x); xbv.y = f2bf(xv.y);
    xbv.z = f2bf(xv.z); xbv.w = f2bf(xv.w);
    *(ushort4*)(xb + (size_t)t * DIM + d4 * 4) = xbv;
#pragma unroll
    for (int e = 0; e < NE; e++) {
      const float4 wv4 = *(const float4*)&sgwT[e][d4 * 4];  // ds_read_b128, no conflict
      acc[e] += xv.x * wv4.x + xv.y * wv4.y + xv.z * wv4.z + xv.w * wv4.w;
    }
  }
#pragma unroll
  for (int e = 0; e < NE; e++)
#pragma unroll
    for (int s = 32; s; s >>= 1) acc[e] += __shfl_xor(acc[e], s, 64);

  if (lane == 0) {
    float l[NE], m = -1e30f;
#pragma unroll
    for (int e = 0; e < NE; e++) { l[e] = acc[e] + gb[e]; m = fmaxf(m, l[e]); }
    float p[NE], sum = 0.f;
#pragma unroll
    for (int e = 0; e < NE; e++) { p[e] = __expf(l[e] - m); sum += p[e]; }
    const float inv = 1.f / sum;
    float s[NE];
#pragma unroll
    for (int e = 0; e < NE; e++) { s[e] = p[e] * inv; scores[t * NE + e] = s[e]; }
    int i1 = 0;
    for (int e = 1; e < NE; e++) if (s[e] > s[i1]) i1 = e;
    int i2 = -1;
    for (int e = 0; e < NE; e++) {
      if (e == i1) continue;
      if (i2 < 0 || s[e] > s[i2]) i2 = e;
    }
    route_e[t * 2] = i1; route_e[t * 2 + 1] = i2;
    route_w[t * 2] = s[i1]; route_w[t * 2 + 1] = s[i2];
  }
}

// ---------------------------------------------------------------------------
// finalize: usage -> lb_loss (d_out tail); counts via route_e histogram;
// prefix offsets; cursors. Writes every ctrl field (no memset needed).
// ---------------------------------------------------------------------------
__global__ void finalize_kernel(const float* __restrict__ scores,
                                const int* __restrict__ route_e,
                                int* __restrict__ ctrl,
                                float* __restrict__ out_lb) {
  __shared__ float red[1024];
  __shared__ int hist[NE];
  const int tid = threadIdx.x;
  if (tid < NE) hist[tid] = 0;
  const int e = tid & 7, row = tid >> 3;
  float s = 0.f;
  for (int i = 0; i < 64; i++) s += scores[(size_t)(row + i * 128) * NE + e];
  red[tid] = s;
  __syncthreads();  // hist zero + red visible
#pragma unroll
  for (int i = 0; i < 16; i++)
    atomicAdd(&hist[route_e[i * 1024 + tid]], 1);
  for (int st = 512; st >= 8; st >>= 1) {
    __syncthreads();
    if (tid < st) red[tid] += red[tid + st];
  }
  __syncthreads();
  if (tid == 0) {
    float lb = 0.f;
    for (int ee = 0; ee < NE; ee++) {
      const float u = red[ee] * (1.f / 8192.f);
      lb -= u * __logf(u + 1e-9f);
    }
    *out_lb = lb;
    int o = 0;
    for (int ee = 0; ee < NE; ee++) {
      ctrl[ee] = hist[ee];    // counts
      ctrl[8 + ee] = o;       // offsets
      ctrl[17 + ee] = o;      // cursors
      o += hist[ee];
    }
    ctrl[16] = o;
  }
}

// ---------------------------------------------------------------------------
// scatter: build per-expert compacted token lists + inverse map pair_pos
// ---------------------------------------------------------------------------
__global__ void scatter_kernel(const int* __restrict__ route_e,
                               const float* __restrict__ route_w,
                               int* __restrict__ ctrl,
                               int* __restrict__ tok_list,
                               float* __restrict__ pair_w,
                               int* __restrict__ pair_pos) {
  const int t = blockIdx.x * 256 + threadIdx.x;
  if (t >= NTOK) return;
#pragma unroll
  for (int k = 0; k < 2; k++) {
    const int e = route_e[t * 2 + k];
    const int p = atomicAdd(&ctrl[17 + e], 1);
    tok_list[p] = t;
    pair_w[p] = route_w[t * 2 + k] * 0.70710678118654752f;  // comb * 1/sqrt(2)
    pair_pos[t * 2 + k] = p;
  }
}

// ---------------------------------------------------------------------------
// stage1 (FUSED): act = (X@W1+b1) * silu(X@W2+b2) for routed rows (bf16)
// grid (16, 32, 8), block 512. M=256 x N=128 tile, BK=64, 2x4 waves,
// per-wave 128 tokens x 32 hcols, dual acc ah/ag = 128 f32 regs.
// Swapped operands: mfma(A=W-frag, B=X-frag) -> lane acc[rg] = 4 consecutive
// hcols for one token -> ushort4 stores (q-groups merge to 32B/token).
// ---------------------------------------------------------------------------
__global__ __launch_bounds__(512) void stage1_kernel(
    const unsigned short* __restrict__ xb, const unsigned short* __restrict__ w1bt,
    const unsigned short* __restrict__ w2bt, const float* __restrict__ b1,
    const float* __restrict__ b2, const int* __restrict__ tok_list,
    const int* __restrict__ ctrl, unsigned short* __restrict__ act) {
  const int e = blockIdx.z;
  const int cnt = ctrl[e];
  const int ytile = blockIdx.y;
  if (ytile * 256 >= cnt) return;
  const int off = ctrl[8 + e];
  const int rows = min(256, cnt - ytile * 256);
  const int h0 = blockIdx.x * 128;

  __shared__ unsigned short sX[2][256 * 64];   // 64 KB
  __shared__ unsigned short sW1[2][128 * 64];  // 32 KB
  __shared__ unsigned short sW2[2][128 * 64];  // 32 KB

  const int tid = threadIdx.x;
  const int wv = tid >> 6, lane = tid & 63;
  const int rr = tid >> 3;
  const int c8 = ((tid & 7) ^ (rr & 7)) * 8;  // swizzled chunk offset (shorts)

  const unsigned short* w1p = w1bt + (size_t)e * HID * DIM + (size_t)h0 * DIM;
  const unsigned short* w2p = w2bt + (size_t)e * HID * DIM + (size_t)h0 * DIM;
  const unsigned short* gx[4];
  const unsigned short* gw1[2];
  const unsigned short* gw2[2];
#pragma unroll
  for (int r = 0; r < 4; r++)
    gx[r] = xb + (size_t)tok_list[off + ytile * 256 + min(rr + r * 64, rows - 1)] * DIM + c8;
#pragma unroll
  for (int r = 0; r < 2; r++) {
    gw1[r] = w1p + (size_t)(rr + r * 64) * DIM + c8;
    gw2[r] = w2p + (size_t)(rr + r * 64) * DIM + c8;
  }

  f32x4 ah[8][2], ag[8][2];
#pragma unroll
  for (int i = 0; i < 8; i++)
#pragma unroll
    for (int j = 0; j < 2; j++) {
      ah[i][j] = (f32x4){0.f, 0.f, 0.f, 0.f};
      ag[i][j] = (f32x4){0.f, 0.f, 0.f, 0.f};
    }

  const int wr = wv >> 2, wc = wv & 3;
  const int l15 = lane & 15, q = lane >> 4, r7 = lane & 7;

  // prologue: stage K-tile 0 into buf0
#pragma unroll
  for (int r = 0; r < 4; r++) {
    async16(gx[r], sX[0] + (r * 512 + wv * 64) * 8);
    gx[r] += 64;
  }
#pragma unroll
  for (int r = 0; r < 2; r++) {
    async16(gw1[r], sW1[0] + (r * 512 + wv * 64) * 8);
    async16(gw2[r], sW2[0] + (r * 512 + wv * 64) * 8);
    gw1[r] += 64; gw2[r] += 64;
  }
  __syncthreads();

  const int NT = DIM / 64;
  for (int t = 0; t < NT; t++) {
    const int cur = t & 1;
    if (t + 1 < NT) {
#pragma unroll
      for (int r = 0; r < 4; r++) {
        async16(gx[r], sX[cur ^ 1] + (r * 512 + wv * 64) * 8);
        gx[r] += 64;
      }
#pragma unroll
      for (int r = 0; r < 2; r++) {
        async16(gw1[r], sW1[cur ^ 1] + (r * 512 + wv * 64) * 8);
        async16(gw2[r], sW2[cur ^ 1] + (r * 512 + wv * 64) * 8);
        gw1[r] += 64; gw2[r] += 64;
      }
    }
#pragma unroll
    for (int kk = 0; kk < 2; kk++) {
      const int pch = ((kk * 4 + q) ^ r7) * 8;
      bf16x8 bx[8], a1[2], a2[2];
#pragma unroll
      for (int i = 0; i < 8; i++)
        bx[i] = *(const bf16x8*)(sX[cur] + (wr * 128 + i * 16 + l15) * 64 + pch);
#pragma unroll
      for (int j = 0; j < 2; j++) {
        a1[j] = *(const bf16x8*)(sW1[cur] + (wc * 32 + j * 16 + l15) * 64 + pch);
        a2[j] = *(const bf16x8*)(sW2[cur] + (wc * 32 + j * 16 + l15) * 64 + pch);
      }
#pragma unroll
      for (int i = 0; i < 8; i++)
#pragma unroll
        for (int j = 0; j < 2; j++) {
          ah[i][j] = __builtin_amdgcn_mfma_f32_16x16x32_bf16(a1[j], bx[i], ah[i][j], 0, 0, 0);
          ag[i][j] = __builtin_amdgcn_mfma_f32_16x16x32_bf16(a2[j], bx[i], ag[i][j], 0, 0, 0);
        }
    }
    __syncthreads();
  }

  // epilogue: out[token][hcol..hcol+3] = (h+b1) * silu(g+b2), ushort4 stores
  f32x4 b1v[2], b2v[2];
#pragma unroll
  for (int j = 0; j < 2; j++) {
    const int hc = h0 + wc * 32 + j * 16 + q * 4;
    b1v[j] = *(const f32x4*)(b1 + e * HID + hc);
    b2v[j] = *(const f32x4*)(b2 + e * HID + hc);
  }
#pragma unroll
  for (int i = 0; i < 8; i++) {
    const int trow = wr * 128 + i * 16 + l15;
    if (trow < rows) {
      const size_t gp = (size_t)(off + ytile * 256 + trow) * HID;
#pragma unroll
      for (int j = 0; j < 2; j++) {
        const int hc = h0 + wc * 32 + j * 16 + q * 4;
        ushort4 o;
        {
          const float hh = ah[i][j][0] + b1v[j][0];
          const float gg = ag[i][j][0] + b2v[j][0];
          o.x = f2bf(hh * (gg / (1.f + __expf(-gg))));
        }
        {
          const float hh = ah[i][j][1] + b1v[j][1];
          const float gg = ag[i][j][1] + b2v[j][1];
          o.y = f2bf(hh * (gg / (1.f + __expf(-gg))));
        }
        {
          const float hh = ah[i][j][2] + b1v[j][2];
          const float gg = ag[i][j][2] + b2v[j][2];
          o.z = f2bf(hh * (gg / (1.f + __expf(-gg))));
        }
        {
          const float hh = ah[i][j][3] + b1v[j][3];
          const float gg = ag[i][j][3] + b2v[j][3];
          o.w = f2bf(hh * (gg / (1.f + __expf(-gg))));
        }
        *(ushort4*)(act + gp + hc) = o;
      }
    }
  }
}

// ---------------------------------------------------------------------------
// stage2 (store path): pair_out[pr] = (act @ W3 + b3) * wt  (bf16)
// grid (4, 32, 8), block 512. K = HID. 256x256 tile, 2x4 waves, acc[8][4].
// ---------------------------------------------------------------------------
__global__ __launch_bounds__(512) void stage2s_kernel(
    const unsigned short* __restrict__ act, const unsigned short* __restrict__ w3bt,
    const float* __restrict__ b3, const float* __restrict__ pair_w,
    const int* __restrict__ ctrl, unsigned short* __restrict__ pair_out) {
  const int e = blockIdx.z;
  const int cnt = ctrl[e];
  const int ytile = blockIdx.y;
  if (ytile * 256 >= cnt) return;
  const int off = ctrl[8 + e];
  const int rows = min(256, cnt - ytile * 256);
  const int d0 = blockIdx.x * 256;
  const int rbase = off + ytile * 256;

  __shared__ unsigned short sA[2][256 * 64];
  __shared__ unsigned short sW[2][256 * 64];

  const int tid = threadIdx.x;
  const int wv = tid >> 6, lane = tid & 63;
  const int rr = tid >> 3;
  const int c8 = ((tid & 7) ^ (rr & 7)) * 8;
  const unsigned short* w3p = w3bt + (size_t)e * DIM * HID + (size_t)d0 * HID;
  const unsigned short* ga[4];
  const unsigned short* gw[4];
#pragma unroll
  for (int r = 0; r < 4; r++) {
    const int row = rr + r * 64;
    ga[r] = act + (size_t)(rbase + min(row, rows - 1)) * HID + c8;
    gw[r] = w3p + (size_t)row * HID + c8;
  }

  f32x4 acc[8][4];
#pragma unroll
  for (int i = 0; i < 8; i++)
#pragma unroll
    for (int j = 0; j < 4; j++) acc[i][j] = (f32x4){0.f, 0.f, 0.f, 0.f};

  const int wr = wv >> 2, wc = wv & 3;
  const int l15 = lane & 15, q = lane >> 4, r7 = lane & 7;

#pragma unroll
  for (int r = 0; r < 4; r++) {
    async16(ga[r], sA[0] + (r * 512 + wv * 64) * 8);
    async16(gw[r], sW[0] + (r * 512 + wv * 64) * 8);
    ga[r] += 64; gw[r] += 64;
  }
  __syncthreads();

  const int NT = HID / 64;
  for (int t = 0; t < NT; t++) {
    const int cur = t & 1;
    if (t + 1 < NT) {
#pragma unroll
      for (int r = 0; r < 4; r++) {
        async16(ga[r], sA[cur ^ 1] + (r * 512 + wv * 64) * 8);
        async16(gw[r], sW[cur ^ 1] + (r * 512 + wv * 64) * 8);
        ga[r] += 64; gw[r] += 64;
      }
    }
#pragma unroll
    for (int kk = 0; kk < 2; kk++) {
      const int pch = ((kk * 4 + q) ^ r7) * 8;
      bf16x8 af[8], bf[4];
#pragma unroll
      for (int i = 0; i < 8; i++)
        af[i] = *(const bf16x8*)(sA[cur] + (wr * 128 + i * 16 + l15) * 64 + pch);
#pragma unroll
      for (int j = 0; j < 4; j++)
        bf[j] = *(const bf16x8*)(sW[cur] + (wc * 64 + j * 16 + l15) * 64 + pch);
#pragma unroll
      for (int i = 0; i < 8; i++)
#pragma unroll
        for (int j = 0; j < 4; j++)
          acc[i][j] =
              __builtin_amdgcn_mfma_f32_16x16x32_bf16(af[i], bf[j], acc[i][j], 0, 0, 0);
    }
    __syncthreads();
  }

#pragma unroll
  for (int i = 0; i < 8; i++)
#pragma unroll
    for (int rg = 0; rg < 4; rg++) {
      const int row = wr * 128 + i * 16 + q * 4 + rg;
      if (row < rows) {
        const int pr = rbase + row;
        const float wt = pair_w[pr];
#pragma unroll
        for (int j = 0; j < 4; j++) {
          const int dcol = d0 + wc * 64 + j * 16 + l15;
          pair_out[(size_t)pr * DIM + dcol] = f2bf((acc[i][j][rg] + b3[e * DIM + dcol]) * wt);
        }
      }
    }
}

// ---------------------------------------------------------------------------
// stage2 (atomic fallback): out[tok] += (act @ W3 + b3) * wt
// ---------------------------------------------------------------------------
__global__ __launch_bounds__(512) void stage2a_kernel(
    const unsigned short* __restrict__ act, const unsigned short* __restrict__ w3bt,
    const float* __restrict__ b3, const int* __restrict__ tok_list,
    const float* __restrict__ pair_w, const int* __restrict__ ctrl,
    float* __restrict__ out) {
  const int e = blockIdx.z;
  const int cnt = ctrl[e];
  const int ytile = blockIdx.y;
  if (ytile * 256 >= cnt) return;
  const int off = ctrl[8 + e];
  const int rows = min(256, cnt - ytile * 256);
  const int d0 = blockIdx.x * 256;
  const int rbase = off + ytile * 256;

  __shared__ unsigned short sA[2][256 * 64];
  __shared__ unsigned short sW[2][256 * 64];

  const int tid = threadIdx.x;
  const int wv = tid >> 6, lane = tid & 63;
  const int rr = tid >> 3;
  const int c8 = ((tid & 7) ^ (rr & 7)) * 8;
  const unsigned short* w3p = w3bt + (size_t)e * DIM * HID + (size_t)d0 * HID;
  const unsigned short* ga[4];
  const unsigned short* gw[4];
#pragma unroll
  for (int r = 0; r < 4; r++) {
    const int row = rr + r * 64;
    ga[r] = act + (size_t)(rbase + min(row, rows - 1)) * HID + c8;
    gw[r] = w3p + (size_t)row * HID + c8;
  }

  f32x4 acc[8][4];
#pragma unroll
  for (int i = 0; i < 8; i++)
#pragma unroll
    for (int j = 0; j < 4; j++) acc[i][j] = (f32x4){0.f, 0.f, 0.f, 0.f};

  const int wr = wv >> 2, wc = wv & 3;
  const int l15 = lane & 15, q = lane >> 4, r7 = lane & 7;

#pragma unroll
  for (int r = 0; r < 4; r++) {
    async16(ga[r], sA[0] + (r * 512 + wv * 64) * 8);
    async16(gw[r], sW[0] + (r * 512 + wv * 64) * 8);
    ga[r] += 64; gw[r] += 64;
  }
  __syncthreads();

  const int NT = HID / 64;
  for (int t = 0; t < NT; t++) {
    const int cur = t & 1;
    if (t + 1 < NT) {
#pragma unroll
      for (int r = 0; r < 4; r++) {
        async16(ga[r], sA[cur ^ 1] + (r * 512 + wv * 64) * 8);
        async16(gw[r], sW[cur ^ 1] + (r * 512 + wv * 64) * 8);
        ga[r] += 64; gw[r] += 64;
      }
    }
#pragma unroll
    for (int kk = 0; kk < 2; kk++) {
      const int pch = ((kk * 4 + q) ^ r7) * 8;
      bf16x8 af[8], bf[4];
#pragma unroll
      for (int i = 0; i < 8; i++)
        af[i] = *(const bf16x8*)(sA[cur] + (wr * 128 + i * 16 + l15) * 64 + pch);
#pragma unroll
      for (int j = 0; j < 4; j++)
        bf[j] = *(const bf16x8*)(sW[cur] + (wc * 64 + j * 16 + l15) * 64 + pch);
#pragma unroll
      for (int i = 0; i < 8; i++)
#pragma unroll
        for (int j = 0; j < 4; j++)
          acc[i][j] =
              __builtin_amdgcn_mfma_f32_16x16x32_bf16(af[i], bf[j], acc[i][j], 0, 0, 0);
    }
    __syncthreads();
  }

#pragma unroll
  for (int i = 0; i < 8; i++)
#pragma unroll
    for (int rg = 0; rg < 4; rg++) {
      const int row = wr * 128 + i * 16 + q * 4 + rg;
      if (row < rows) {
        const int pr = rbase + row;
        const int tok = tok_list[pr];
        const float wt = pair_w[pr];
#pragma unroll
        for (int j = 0; j < 4; j++) {
          const int dcol = d0 + wc * 64 + j * 16 + l15;
          atomicAdd(out + (size_t)tok * DIM + dcol, (acc[i][j][rg] + b3[e * DIM + dcol]) * wt);
        }
      }
    }
}

// ---------------------------------------------------------------------------
// combine: out[t] = pair_out[pos(t,0)] + pair_out[pos(t,1)]. grid NTOK x 256.
// ---------------------------------------------------------------------------
__global__ __launch_bounds__(256) void combine_kernel(
    const unsigned short* __restrict__ pair_out, const int* __restrict__ pair_pos,
    float* __restrict__ out) {
  const int t = blockIdx.x;
  const int d = threadIdx.x * 4;
  const int p0 = pair_pos[t * 2], p1 = pair_pos[t * 2 + 1];
  const ushort4 a = *(const ushort4*)(pair_out + (size_t)p0 * DIM + d);
  const ushort4 b = *(const ushort4*)(pair_out + (size_t)p1 * DIM + d);
  float4 r;
  r.x = bf2f(a.x) + bf2f(b.x);
  r.y = bf2f(a.y) + bf2f(b.y);
  r.z = bf2f(a.z) + bf2f(b.z);
  r.w = bf2f(a.w) + bf2f(b.w);
  *(float4*)(out + (size_t)t * DIM + d) = r;
}

// ---------------------------------------------------------------------------
// workspace layout (bytes)
// ---------------------------------------------------------------------------
static const size_t SZ_XB  = (size_t)NTOK * DIM * 2;        // 16 MB
static const size_t SZ_W   = (size_t)NE * DIM * HID * 2;    // 32 MB each
static const size_t SZ_ACT = (size_t)NPAIR * HID * 2;       // 64 MB
static const size_t OFF_XB  = 0;
static const size_t OFF_W1  = OFF_XB + SZ_XB;
static const size_t OFF_W2  = OFF_W1 + SZ_W;
static const size_t OFF_W3  = OFF_W2 + SZ_W;
static const size_t OFF_ACT = OFF_W3 + SZ_W;
static const size_t OFF_SC  = OFF_ACT + SZ_ACT;
static const size_t OFF_RE  = OFF_SC + (size_t)NTOK * NE * 4;
static const size_t OFF_RW  = OFF_RE + (size_t)NPAIR * 4;
static const size_t OFF_TL  = OFF_RW + (size_t)NPAIR * 4;
static const size_t OFF_PW  = OFF_TL + (size_t)NPAIR * 4;
static const size_t OFF_PP  = OFF_PW + (size_t)NPAIR * 4;
static const size_t OFF_CT  = OFF_PP + (size_t)NPAIR * 4;
static const size_t WS_BASE = OFF_CT + 128;
static const size_t OFF_PO  = WS_BASE;                      // pair_out bf16, 32 MB
static const size_t WS_FULL = OFF_PO + (size_t)NPAIR * DIM * 2;

extern "C" void kernel_launch(void* const* d_in, const int* in_sizes, int n_in,
                              void* d_out, int out_size, void* d_ws, size_t ws_size,
                              hipStream_t stream) {
  const float* x      = (const float*)d_in[0];
  const float* gate_w = (const float*)d_in[1];
  const float* gate_b = (const float*)d_in[2];
  const float* w1     = (const float*)d_in[3];
  const float* b1     = (const float*)d_in[4];
  const float* w2     = (const float*)d_in[5];
  const float* b2     = (const float*)d_in[6];
  const float* w3     = (const float*)d_in[7];
  const float* b3     = (const float*)d_in[8];
  float* out = (float*)d_out;

  if (ws_size < WS_BASE) {
    fprintf(stderr, "kernel_launch: ws_size %zu < needed %zu\n", ws_size, WS_BASE);
    return;
  }
  const bool store_path = (ws_size >= WS_FULL);

  char* ws = (char*)d_ws;
  unsigned short* xb   = (unsigned short*)(ws + OFF_XB);
  unsigned short* w1bt = (unsigned short*)(ws + OFF_W1);
  unsigned short* w2bt = (unsigned short*)(ws + OFF_W2);
  unsigned short* w3bt = (unsigned short*)(ws + OFF_W3);
  unsigned short* act  = (unsigned short*)(ws + OFF_ACT);
  float* scores        = (float*)(ws + OFF_SC);
  int* route_e         = (int*)(ws + OFF_RE);
  float* route_w       = (float*)(ws + OFF_RW);
  int* tok_list        = (int*)(ws + OFF_TL);
  float* pair_w        = (float*)(ws + OFF_PW);
  int* pair_pos        = (int*)(ws + OFF_PP);
  int* ctrl            = (int*)(ws + OFF_CT);
  unsigned short* pout = (unsigned short*)(ws + OFF_PO);

  if (!store_path)
    hipMemsetAsync(d_out, 0, (size_t)out_size * sizeof(float), stream);

  prep_kernel<<<dim3(2048, 24), 256, 0, stream>>>(w1, w2, w3, w1bt, w2bt, w3bt);
  gate_kernel<<<2048, 256, 0, stream>>>(x, gate_w, gate_b, xb, scores, route_e,
                                        route_w);
  finalize_kernel<<<1, 1024, 0, stream>>>(scores, route_e, ctrl, out + (out_size - 1));
  scatter_kernel<<<32, 256, 0, stream>>>(route_e, route_w, ctrl, tok_list, pair_w,
                                         pair_pos);
  stage1_kernel<<<dim3(16, 32, 8), 512, 0, stream>>>(xb, w1bt, w2bt, b1, b2,
                                                     tok_list, ctrl, act);
  if (store_path) {
    stage2s_kernel<<<dim3(4, 32, 8), 512, 0, stream>>>(act, w3bt, b3, pair_w, ctrl, pout);
    combine_kernel<<<NTOK, 256, 0, stream>>>(pout, pair_pos, out);
  } else {
    stage2a_kernel<<<dim3(4, 32, 8), 512, 0, stream>>>(act, w3bt, b3, tok_list,
                                                       pair_w, ctrl, out);
  }
}

// Round 4
// 640.919 us; speedup vs baseline: 1.2632x; 1.0294x over previous
//
#include <hip/hip_runtime.h>
#include <cstdio>

#define NTOK 8192
#define DIM 1024
#define HID 2048
#define NE 8
#define NPAIR (NTOK * 2)

typedef __attribute__((ext_vector_type(8))) short bf16x8;
typedef __attribute__((ext_vector_type(4))) float f32x4;

typedef const __attribute__((address_space(1))) void* gas_ptr;
typedef __attribute__((address_space(3))) void* las_ptr;

__device__ __forceinline__ void async16(const void* g, void* s) {
  // direct global->LDS, 16B per lane; LDS dest = wave-uniform base + lane*16
  __builtin_amdgcn_global_load_lds((gas_ptr)g, (las_ptr)s, 16, 0, 0);
}

__device__ __forceinline__ unsigned short f2bf(float f) {
  unsigned int u = __float_as_uint(f);
  u = (u + 0x7fff + ((u >> 16) & 1)) >> 16;  // RNE
  return (unsigned short)u;
}

__device__ __forceinline__ float bf2f(unsigned short u) {
  return __uint_as_float((unsigned int)u << 16);
}

// r9: counted-vmcnt deep pipeline (T3+T4+T5 port of m201/m248 template).
// BK=32, 4 LDS buffers, stage 3 K-tiles ahead, vmcnt(8) steady state (never
// 0 in main loop). Per K-tile/thread: exactly 4 global_load_lds (vmcnt
// currency), 12 ds_read_b128, 32 MFMA/wave. Raw s_barrier + memory-clobber
// fences (NO __syncthreads in loop: it drains vmcnt(0) = the 2-phase stall,
// m233: ~72% of critical path). Phase shape per m201: {ds_read || issue ->
// bar -> lgkm0+sched_barrier -> setprio MFMA -> counted vmcnt -> fence ->
// bar}. 64B LDS rows: logical chunk = phys ^ ((row>>1)&3) -> 8 bank groups,
// conflict-free b128 frag reads; staging source pre-swizzled, LDS linear.

#define S_BARRIER __builtin_amdgcn_s_barrier()
#define VM_WAIT(N) asm volatile("s_waitcnt vmcnt(" #N ")" ::: "memory")
#define LGKM0 asm volatile("s_waitcnt lgkmcnt(0)" ::: "memory")
#define CFENCE asm volatile("" ::: "memory")

// ---------------------------------------------------------------------------
// prep: w1[e][d][h] -> w1bt[e][h][d] (bf16), w2 same, w3[e][h][d] -> w3bt[e][d][h]
// ---------------------------------------------------------------------------
__global__ __launch_bounds__(256) void prep_kernel(
    const float* __restrict__ w1, const float* __restrict__ w2,
    const float* __restrict__ w3, unsigned short* __restrict__ w1bt,
    unsigned short* __restrict__ w2bt, unsigned short* __restrict__ w3bt) {
  const int z = blockIdx.y;
  const int m = z >> 3, e = z & 7;
  int R, C;
  const float* in;
  unsigned short* outp;
  if (m == 0)      { R = DIM; C = HID; in = w1; outp = w1bt; }
  else if (m == 1) { R = DIM; C = HID; in = w2; outp = w2bt; }
  else             { R = HID; C = DIM; in = w3; outp = w3bt; }
  in += (size_t)e * DIM * HID;
  outp += (size_t)e * DIM * HID;

  const int tilesx = C >> 5;
  const int c0 = (blockIdx.x % tilesx) * 32;
  const int r0 = (blockIdx.x / tilesx) * 32;

  __shared__ float tile[32][33];
  const int c = threadIdx.x & 31, rr = threadIdx.x >> 5;
#pragma unroll
  for (int i = 0; i < 4; i++) {
    const int r = rr + i * 8;
    tile[r][c] = in[(size_t)(r0 + r) * C + c0 + c];
  }
  __syncthreads();
#pragma unroll
  for (int i = 0; i < 4; i++) {
    const int cc2 = rr + i * 8;  // column of original = row of output
    outp[(size_t)(c0 + cc2) * R + r0 + c] = f2bf(tile[c][cc2]);
  }
}

// ---------------------------------------------------------------------------
// gating: 1 wave per token. Transposed gate_w in LDS -> conflict-free b128
// reads. No atomics here (counts in finalize).
// ---------------------------------------------------------------------------
__global__ __launch_bounds__(256) void gate_kernel(
    const float* __restrict__ x, const float* __restrict__ gw,
    const float* __restrict__ gb, unsigned short* __restrict__ xb,
    float* __restrict__ scores, int* __restrict__ route_e,
    float* __restrict__ route_w) {
  __shared__ float sgwT[NE][DIM];  // 32 KB, transposed [e][d]
  const int tid = threadIdx.x;
#pragma unroll
  for (int i = 0; i < 8; i++) {
    const int j = i * 256 + tid;               // float4 index into gw[DIM][NE]
    const float4 v = ((const float4*)gw)[j];
    const int d = j >> 1, e0 = (j & 1) * 4;    // 2-way bank alias on store: free
    sgwT[e0 + 0][d] = v.x; sgwT[e0 + 1][d] = v.y;
    sgwT[e0 + 2][d] = v.z; sgwT[e0 + 3][d] = v.w;
  }
  __syncthreads();

  const int wv = tid >> 6, lane = tid & 63;
  const int t = blockIdx.x * 4 + wv;
  float acc[NE] = {0.f, 0.f, 0.f, 0.f, 0.f, 0.f, 0.f, 0.f};
  const float4* x4 = (const float4*)(x + (size_t)t * DIM);
#pragma unroll
  for (int i = 0; i < 4; i++) {
    const float4 xv = x4[i * 64 + lane];
    const int d4 = i * 64 + lane;              // float4 index; byte addr lane*16
    ushort4 xbv;
    xbv.x = f2bf(xv.x); xbv.y = f2bf(xv.y);
    xbv.z = f2bf(xv.z); xbv.w = f2bf(xv.w);
    *(ushort4*)(xb + (size_t)t * DIM + d4 * 4) = xbv;
#pragma unroll
    for (int e = 0; e < NE; e++) {
      const float4 wv4 = *(const float4*)&sgwT[e][d4 * 4];  // ds_read_b128, no conflict
      acc[e] += xv.x * wv4.x + xv.y * wv4.y + xv.z * wv4.z + xv.w * wv4.w;
    }
  }
#pragma unroll
  for (int e = 0; e < NE; e++)
#pragma unroll
    for (int s = 32; s; s >>= 1) acc[e] += __shfl_xor(acc[e], s, 64);

  if (lane == 0) {
    float l[NE], m = -1e30f;
#pragma unroll
    for (int e = 0; e < NE; e++) { l[e] = acc[e] + gb[e]; m = fmaxf(m, l[e]); }
    float p[NE], sum = 0.f;
#pragma unroll
    for (int e = 0; e < NE; e++) { p[e] = __expf(l[e] - m); sum += p[e]; }
    const float inv = 1.f / sum;
    float s[NE];
#pragma unroll
    for (int e = 0; e < NE; e++) { s[e] = p[e] * inv; scores[t * NE + e] = s[e]; }
    int i1 = 0;
    for (int e = 1; e < NE; e++) if (s[e] > s[i1]) i1 = e;
    int i2 = -1;
    for (int e = 0; e < NE; e++) {
      if (e == i1) continue;
      if (i2 < 0 || s[e] > s[i2]) i2 = e;
    }
    route_e[t * 2] = i1; route_e[t * 2 + 1] = i2;
    route_w[t * 2] = s[i1]; route_w[t * 2 + 1] = s[i2];
  }
}

// ---------------------------------------------------------------------------
// finalize: usage -> lb_loss (d_out tail); counts via route_e histogram;
// prefix offsets; cursors. Writes every ctrl field (no memset needed).
// ---------------------------------------------------------------------------
__global__ void finalize_kernel(const float* __restrict__ scores,
                                const int* __restrict__ route_e,
                                int* __restrict__ ctrl,
                                float* __restrict__ out_lb) {
  __shared__ float red[1024];
  __shared__ int hist[NE];
  const int tid = threadIdx.x;
  if (tid < NE) hist[tid] = 0;
  const int e = tid & 7, row = tid >> 3;
  float s = 0.f;
  for (int i = 0; i < 64; i++) s += scores[(size_t)(row + i * 128) * NE + e];
  red[tid] = s;
  __syncthreads();  // hist zero + red visible
#pragma unroll
  for (int i = 0; i < 16; i++)
    atomicAdd(&hist[route_e[i * 1024 + tid]], 1);
  for (int st = 512; st >= 8; st >>= 1) {
    __syncthreads();
    if (tid < st) red[tid] += red[tid + st];
  }
  __syncthreads();
  if (tid == 0) {
    float lb = 0.f;
    for (int ee = 0; ee < NE; ee++) {
      const float u = red[ee] * (1.f / 8192.f);
      lb -= u * __logf(u + 1e-9f);
    }
    *out_lb = lb;
    int o = 0;
    for (int ee = 0; ee < NE; ee++) {
      ctrl[ee] = hist[ee];    // counts
      ctrl[8 + ee] = o;       // offsets
      ctrl[17 + ee] = o;      // cursors
      o += hist[ee];
    }
    ctrl[16] = o;
  }
}

// ---------------------------------------------------------------------------
// scatter: build per-expert compacted token lists + inverse map pair_pos
// ---------------------------------------------------------------------------
__global__ void scatter_kernel(const int* __restrict__ route_e,
                               const float* __restrict__ route_w,
                               int* __restrict__ ctrl,
                               int* __restrict__ tok_list,
                               float* __restrict__ pair_w,
                               int* __restrict__ pair_pos) {
  const int t = blockIdx.x * 256 + threadIdx.x;
  if (t >= NTOK) return;
#pragma unroll
  for (int k = 0; k < 2; k++) {
    const int e = route_e[t * 2 + k];
    const int p = atomicAdd(&ctrl[17 + e], 1);
    tok_list[p] = t;
    pair_w[p] = route_w[t * 2 + k] * 0.70710678118654752f;  // comb * 1/sqrt(2)
    pair_pos[t * 2 + k] = p;
  }
}

// ---------------------------------------------------------------------------
// stage1 (FUSED): act = (X@W1+b1) * silu(X@W2+b2) for routed rows (bf16)
// grid (16, 32, 8), block 512. M=256 x N=128 tile, BK=32, 4-deep pipeline.
// Per wave: 128 tok x 32 hid, dual acc ah/ag. Swapped operands mfma(W,X):
// lane acc = 4 consecutive hcols -> ushort4 stores.
// ---------------------------------------------------------------------------
__global__ __launch_bounds__(512) void stage1_kernel(
    const unsigned short* __restrict__ xb, const unsigned short* __restrict__ w1bt,
    const unsigned short* __restrict__ w2bt, const float* __restrict__ b1,
    const float* __restrict__ b2, const int* __restrict__ tok_list,
    const int* __restrict__ ctrl, unsigned short* __restrict__ act) {
  const int e = blockIdx.z;
  const int cnt = ctrl[e];
  const int ytile = blockIdx.y;
  if (ytile * 256 >= cnt) return;
  const int off = ctrl[8 + e];
  const int rows = min(256, cnt - ytile * 256);
  const int h0 = blockIdx.x * 128;

  __shared__ unsigned short sX[4][256 * 32];   // 64 KB
  __shared__ unsigned short sW1[4][128 * 32];  // 32 KB
  __shared__ unsigned short sW2[4][128 * 32];  // 32 KB

  const int tid = threadIdx.x;
  const int wv = tid >> 6, lane = tid & 63;

  // staging: 16B chunk = 8 shorts; 4 chunks/row (BK=32).
  // X: 1024 chunks -> slots tid, tid+512. W1/W2: 512 chunks -> slot tid.
  // logical k-chunk of (row, phys p) = p ^ ((row>>1)&3); for all our slots
  // (row>>1)&3 == (tid>>3)&3 (row = tid>>2 or 128+(tid>>2)).
  const int cl = ((tid & 3) ^ ((tid >> 3) & 3)) * 8;  // k-offset in shorts

  const unsigned short* w1p = w1bt + (size_t)e * HID * DIM + (size_t)h0 * DIM;
  const unsigned short* w2p = w2bt + (size_t)e * HID * DIM + (size_t)h0 * DIM;
  const unsigned short* gx0 =
      xb + (size_t)tok_list[off + ytile * 256 + min(tid >> 2, rows - 1)] * DIM + cl;
  const unsigned short* gx1 =
      xb + (size_t)tok_list[off + ytile * 256 + min(128 + (tid >> 2), rows - 1)] * DIM + cl;
  const unsigned short* gw1 = w1p + (size_t)(tid >> 2) * DIM + cl;
  const unsigned short* gw2 = w2p + (size_t)(tid >> 2) * DIM + cl;

  f32x4 ah[8][2], ag[8][2];
#pragma unroll
  for (int i = 0; i < 8; i++)
#pragma unroll
    for (int j = 0; j < 2; j++) {
      ah[i][j] = (f32x4){0.f, 0.f, 0.f, 0.f};
      ag[i][j] = (f32x4){0.f, 0.f, 0.f, 0.f};
    }

  const int wr = wv >> 2, wc = wv & 3;
  const int l15 = lane & 15, q = lane >> 4;
  // frag read chunk: phys = q ^ ((row>>1)&3); (row>>1)&3 == (l15>>1)&3 for
  // all frag rows (base offsets are multiples of 8).
  const int pch = (q ^ ((l15 >> 1) & 3)) * 8;

#define S1_STAGE(B)                                   \
  do {                                                \
    async16(gx0, sX[B] + (wv * 64) * 8);              \
    async16(gx1, sX[B] + (512 + wv * 64) * 8);        \
    async16(gw1, sW1[B] + (wv * 64) * 8);             \
    async16(gw2, sW2[B] + (wv * 64) * 8);             \
    gx0 += 32; gx1 += 32; gw1 += 32; gw2 += 32;       \
  } while (0)

  // prologue: stage K0,K1,K2 (12 loads in flight)
  S1_STAGE(0); S1_STAGE(1); S1_STAGE(2);
  VM_WAIT(8);  // K0 landed (8 newest = K1,K2 may remain)
  S_BARRIER;
  CFENCE;

  const int NT = DIM / 32;  // 32
  for (int t = 0; t < NT; t++) {
    const int cur = t & 3;
    bf16x8 bx[8], a1[2], a2[2];
    {
      const unsigned short* xs = sX[cur];
      const unsigned short* w1s = sW1[cur];
      const unsigned short* w2s = sW2[cur];
#pragma unroll
      for (int i = 0; i < 8; i++)
        bx[i] = *(const bf16x8*)(xs + (wr * 128 + i * 16 + l15) * 32 + pch);
#pragma unroll
      for (int j = 0; j < 2; j++) {
        a1[j] = *(const bf16x8*)(w1s + (wc * 32 + j * 16 + l15) * 32 + pch);
        a2[j] = *(const bf16x8*)(w2s + (wc * 32 + j * 16 + l15) * 32 + pch);
      }
    }
    if (t < NT - 3) {
      const int nb = (t + 3) & 3;
      S1_STAGE(nb);
    }
    S_BARRIER;
    LGKM0;
    __builtin_amdgcn_sched_barrier(0);
    __builtin_amdgcn_s_setprio(1);
#pragma unroll
    for (int i = 0; i < 8; i++) {
      ah[i][0] = __builtin_amdgcn_mfma_f32_16x16x32_bf16(a1[0], bx[i], ah[i][0], 0, 0, 0);
      ag[i][0] = __builtin_amdgcn_mfma_f32_16x16x32_bf16(a2[0], bx[i], ag[i][0], 0, 0, 0);
      ah[i][1] = __builtin_amdgcn_mfma_f32_16x16x32_bf16(a1[1], bx[i], ah[i][1], 0, 0, 0);
      ag[i][1] = __builtin_amdgcn_mfma_f32_16x16x32_bf16(a2[1], bx[i], ag[i][1], 0, 0, 0);
    }
    __builtin_amdgcn_s_setprio(0);
    // tail: guarantee K_{t+1} before next iter's ds_reads; never drain to 0
    // while loads remain beyond the needed tile.
    if (t < NT - 3) VM_WAIT(8);
    else if (t == NT - 3) VM_WAIT(4);
    else if (t == NT - 2) VM_WAIT(0);
    CFENCE;
    S_BARRIER;
  }
#undef S1_STAGE

  // epilogue: out[token][hcol..hcol+3] = (h+b1) * silu(g+b2), ushort4 stores
  f32x4 b1v[2], b2v[2];
#pragma unroll
  for (int j = 0; j < 2; j++) {
    const int hc = h0 + wc * 32 + j * 16 + q * 4;
    b1v[j] = *(const f32x4*)(b1 + e * HID + hc);
    b2v[j] = *(const f32x4*)(b2 + e * HID + hc);
  }
#pragma unroll
  for (int i = 0; i < 8; i++) {
    const int trow = wr * 128 + i * 16 + l15;
    if (trow < rows) {
      const size_t gp = (size_t)(off + ytile * 256 + trow) * HID;
#pragma unroll
      for (int j = 0; j < 2; j++) {
        const int hc = h0 + wc * 32 + j * 16 + q * 4;
        ushort4 o;
        {
          const float hh = ah[i][j][0] + b1v[j][0];
          const float gg = ag[i][j][0] + b2v[j][0];
          o.x = f2bf(hh * (gg / (1.f + __expf(-gg))));
        }
        {
          const float hh = ah[i][j][1] + b1v[j][1];
          const float gg = ag[i][j][1] + b2v[j][1];
          o.y = f2bf(hh * (gg / (1.f + __expf(-gg))));
        }
        {
          const float hh = ah[i][j][2] + b1v[j][2];
          const float gg = ag[i][j][2] + b2v[j][2];
          o.z = f2bf(hh * (gg / (1.f + __expf(-gg))));
        }
        {
          const float hh = ah[i][j][3] + b1v[j][3];
          const float gg = ag[i][j][3] + b2v[j][3];
          o.w = f2bf(hh * (gg / (1.f + __expf(-gg))));
        }
        *(ushort4*)(act + gp + hc) = o;
      }
    }
  }
}

// ---------------------------------------------------------------------------
// stage2 (store path): pair_out[pr] = (act @ W3 + b3) * wt  (bf16)
// grid (4, 32, 8), block 512. 256x256 tile, BK=32, 4-deep pipeline, K=HID.
// ---------------------------------------------------------------------------
__global__ __launch_bounds__(512) void stage2s_kernel(
    const unsigned short* __restrict__ act, const unsigned short* __restrict__ w3bt,
    const float* __restrict__ b3, const float* __restrict__ pair_w,
    const int* __restrict__ ctrl, unsigned short* __restrict__ pair_out) {
  const int e = blockIdx.z;
  const int cnt = ctrl[e];
  const int ytile = blockIdx.y;
  if (ytile * 256 >= cnt) return;
  const int off = ctrl[8 + e];
  const int rows = min(256, cnt - ytile * 256);
  const int d0 = blockIdx.x * 256;
  const int rbase = off + ytile * 256;

  __shared__ unsigned short sA[4][256 * 32];  // 64 KB
  __shared__ unsigned short sW[4][256 * 32];  // 64 KB

  const int tid = threadIdx.x;
  const int wv = tid >> 6, lane = tid & 63;
  const int cl = ((tid & 3) ^ ((tid >> 3) & 3)) * 8;

  const unsigned short* w3p = w3bt + (size_t)e * DIM * HID + (size_t)d0 * HID;
  const unsigned short* ga0 =
      act + (size_t)(rbase + min(tid >> 2, rows - 1)) * HID + cl;
  const unsigned short* ga1 =
      act + (size_t)(rbase + min(128 + (tid >> 2), rows - 1)) * HID + cl;
  const unsigned short* gw0 = w3p + (size_t)(tid >> 2) * HID + cl;
  const unsigned short* gw1 = w3p + (size_t)(128 + (tid >> 2)) * HID + cl;

  f32x4 acc[8][4];
#pragma unroll
  for (int i = 0; i < 8; i++)
#pragma unroll
    for (int j = 0; j < 4; j++) acc[i][j] = (f32x4){0.f, 0.f, 0.f, 0.f};

  const int wr = wv >> 2, wc = wv & 3;
  const int l15 = lane & 15, q = lane >> 4;
  const int pch = (q ^ ((l15 >> 1) & 3)) * 8;

#define S2_STAGE(B)                                   \
  do {                                                \
    async16(ga0, sA[B] + (wv * 64) * 8);              \
    async16(ga1, sA[B] + (512 + wv * 64) * 8);        \
    async16(gw0, sW[B] + (wv * 64) * 8);              \
    async16(gw1, sW[B] + (512 + wv * 64) * 8);        \
    ga0 += 32; ga1 += 32; gw0 += 32; gw1 += 32;       \
  } while (0)

  S2_STAGE(0); S2_STAGE(1); S2_STAGE(2);
  VM_WAIT(8);
  S_BARRIER;
  CFENCE;

  const int NT = HID / 32;  // 64
  for (int t = 0; t < NT; t++) {
    const int cur = t & 3;
    bf16x8 af[8], bf[4];
    {
      const unsigned short* as = sA[cur];
      const unsigned short* ws = sW[cur];
#pragma unroll
      for (int i = 0; i < 8; i++)
        af[i] = *(const bf16x8*)(as + (wr * 128 + i * 16 + l15) * 32 + pch);
#pragma unroll
      for (int j = 0; j < 4; j++)
        bf[j] = *(const bf16x8*)(ws + (wc * 64 + j * 16 + l15) * 32 + pch);
    }
    if (t < NT - 3) {
      const int nb = (t + 3) & 3;
      S2_STAGE(nb);
    }
    S_BARRIER;
    LGKM0;
    __builtin_amdgcn_sched_barrier(0);
    __builtin_amdgcn_s_setprio(1);
#pragma unroll
    for (int i = 0; i < 8; i++)
#pragma unroll
      for (int j = 0; j < 4; j++)
        acc[i][j] =
            __builtin_amdgcn_mfma_f32_16x16x32_bf16(af[i], bf[j], acc[i][j], 0, 0, 0);
    __builtin_amdgcn_s_setprio(0);
    if (t < NT - 3) VM_WAIT(8);
    else if (t == NT - 3) VM_WAIT(4);
    else if (t == NT - 2) VM_WAIT(0);
    CFENCE;
    S_BARRIER;
  }
#undef S2_STAGE

#pragma unroll
  for (int i = 0; i < 8; i++)
#pragma unroll
    for (int rg = 0; rg < 4; rg++) {
      const int row = wr * 128 + i * 16 + q * 4 + rg;
      if (row < rows) {
        const int pr = rbase + row;
        const float wt = pair_w[pr];
#pragma unroll
        for (int j = 0; j < 4; j++) {
          const int dcol = d0 + wc * 64 + j * 16 + l15;
          pair_out[(size_t)pr * DIM + dcol] = f2bf((acc[i][j][rg] + b3[e * DIM + dcol]) * wt);
        }
      }
    }
}

// ---------------------------------------------------------------------------
// stage2 (atomic fallback): out[tok] += (act @ W3 + b3) * wt
// ---------------------------------------------------------------------------
__global__ __launch_bounds__(512) void stage2a_kernel(
    const unsigned short* __restrict__ act, const unsigned short* __restrict__ w3bt,
    const float* __restrict__ b3, const int* __restrict__ tok_list,
    const float* __restrict__ pair_w, const int* __restrict__ ctrl,
    float* __restrict__ out) {
  const int e = blockIdx.z;
  const int cnt = ctrl[e];
  const int ytile = blockIdx.y;
  if (ytile * 256 >= cnt) return;
  const int off = ctrl[8 + e];
  const int rows = min(256, cnt - ytile * 256);
  const int d0 = blockIdx.x * 256;
  const int rbase = off + ytile * 256;

  __shared__ unsigned short sA[4][256 * 32];
  __shared__ unsigned short sW[4][256 * 32];

  const int tid = threadIdx.x;
  const int wv = tid >> 6, lane = tid & 63;
  const int cl = ((tid & 3) ^ ((tid >> 3) & 3)) * 8;

  const unsigned short* w3p = w3bt + (size_t)e * DIM * HID + (size_t)d0 * HID;
  const unsigned short* ga0 =
      act + (size_t)(rbase + min(tid >> 2, rows - 1)) * HID + cl;
  const unsigned short* ga1 =
      act + (size_t)(rbase + min(128 + (tid >> 2), rows - 1)) * HID + cl;
  const unsigned short* gw0 = w3p + (size_t)(tid >> 2) * HID + cl;
  const unsigned short* gw1 = w3p + (size_t)(128 + (tid >> 2)) * HID + cl;

  f32x4 acc[8][4];
#pragma unroll
  for (int i = 0; i < 8; i++)
#pragma unroll
    for (int j = 0; j < 4; j++) acc[i][j] = (f32x4){0.f, 0.f, 0.f, 0.f};

  const int wr = wv >> 2, wc = wv & 3;
  const int l15 = lane & 15, q = lane >> 4;
  const int pch = (q ^ ((l15 >> 1) & 3)) * 8;

#define S2A_STAGE(B)                                  \
  do {                                                \
    async16(ga0, sA[B] + (wv * 64) * 8);              \
    async16(ga1, sA[B] + (512 + wv * 64) * 8);        \
    async16(gw0, sW[B] + (wv * 64) * 8);              \
    async16(gw1, sW[B] + (512 + wv * 64) * 8);        \
    ga0 += 32; ga1 += 32; gw0 += 32; gw1 += 32;       \
  } while (0)

  S2A_STAGE(0); S2A_STAGE(1); S2A_STAGE(2);
  VM_WAIT(8);
  S_BARRIER;
  CFENCE;

  const int NT = HID / 32;
  for (int t = 0; t < NT; t++) {
    const int cur = t & 3;
    bf16x8 af[8], bf[4];
    {
      const unsigned short* as = sA[cur];
      const unsigned short* ws = sW[cur];
#pragma unroll
      for (int i = 0; i < 8; i++)
        af[i] = *(const bf16x8*)(as + (wr * 128 + i * 16 + l15) * 32 + pch);
#pragma unroll
      for (int j = 0; j < 4; j++)
        bf[j] = *(const bf16x8*)(ws + (wc * 64 + j * 16 + l15) * 32 + pch);
    }
    if (t < NT - 3) {
      const int nb = (t + 3) & 3;
      S2A_STAGE(nb);
    }
    S_BARRIER;
    LGKM0;
    __builtin_amdgcn_sched_barrier(0);
    __builtin_amdgcn_s_setprio(1);
#pragma unroll
    for (int i = 0; i < 8; i++)
#pragma unroll
      for (int j = 0; j < 4; j++)
        acc[i][j] =
            __builtin_amdgcn_mfma_f32_16x16x32_bf16(af[i], bf[j], acc[i][j], 0, 0, 0);
    __builtin_amdgcn_s_setprio(0);
    if (t < NT - 3) VM_WAIT(8);
    else if (t == NT - 3) VM_WAIT(4);
    else if (t == NT - 2) VM_WAIT(0);
    CFENCE;
    S_BARRIER;
  }
#undef S2A_STAGE

#pragma unroll
  for (int i = 0; i < 8; i++)
#pragma unroll
    for (int rg = 0; rg < 4; rg++) {
      const int row = wr * 128 + i * 16 + q * 4 + rg;
      if (row < rows) {
        const int pr = rbase + row;
        const int tok = tok_list[pr];
        const float wt = pair_w[pr];
#pragma unroll
        for (int j = 0; j < 4; j++) {
          const int dcol = d0 + wc * 64 + j * 16 + l15;
          atomicAdd(out + (size_t)tok * DIM + dcol, (acc[i][j][rg] + b3[e * DIM + dcol]) * wt);
        }
      }
    }
}

// ---------------------------------------------------------------------------
// combine: out[t] = pair_out[pos(t,0)] + pair_out[pos(t,1)]. grid NTOK x 256.
// ---------------------------------------------------------------------------
__global__ __launch_bounds__(256) void combine_kernel(
    const unsigned short* __restrict__ pair_out, const int* __restrict__ pair_pos,
    float* __restrict__ out) {
  const int t = blockIdx.x;
  const int d = threadIdx.x * 4;
  const int p0 = pair_pos[t * 2], p1 = pair_pos[t * 2 + 1];
  const ushort4 a = *(const ushort4*)(pair_out + (size_t)p0 * DIM + d);
  const ushort4 b = *(const ushort4*)(pair_out + (size_t)p1 * DIM + d);
  float4 r;
  r.x = bf2f(a.x) + bf2f(b.x);
  r.y = bf2f(a.y) + bf2f(b.y);
  r.z = bf2f(a.z) + bf2f(b.z);
  r.w = bf2f(a.w) + bf2f(b.w);
  *(float4*)(out + (size_t)t * DIM + d) = r;
}

// ---------------------------------------------------------------------------
// workspace layout (bytes)
// ---------------------------------------------------------------------------
static const size_t SZ_XB  = (size_t)NTOK * DIM * 2;        // 16 MB
static const size_t SZ_W   = (size_t)NE * DIM * HID * 2;    // 32 MB each
static const size_t SZ_ACT = (size_t)NPAIR * HID * 2;       // 64 MB
static const size_t OFF_XB  = 0;
static const size_t OFF_W1  = OFF_XB + SZ_XB;
static const size_t OFF_W2  = OFF_W1 + SZ_W;
static const size_t OFF_W3  = OFF_W2 + SZ_W;
static const size_t OFF_ACT = OFF_W3 + SZ_W;
static const size_t OFF_SC  = OFF_ACT + SZ_ACT;
static const size_t OFF_RE  = OFF_SC + (size_t)NTOK * NE * 4;
static const size_t OFF_RW  = OFF_RE + (size_t)NPAIR * 4;
static const size_t OFF_TL  = OFF_RW + (size_t)NPAIR * 4;
static const size_t OFF_PW  = OFF_TL + (size_t)NPAIR * 4;
static const size_t OFF_PP  = OFF_PW + (size_t)NPAIR * 4;
static const size_t OFF_CT  = OFF_PP + (size_t)NPAIR * 4;
static const size_t WS_BASE = OFF_CT + 128;
static const size_t OFF_PO  = WS_BASE;                      // pair_out bf16, 32 MB
static const size_t WS_FULL = OFF_PO + (size_t)NPAIR * DIM * 2;

extern "C" void kernel_launch(void* const* d_in, const int* in_sizes, int n_in,
                              void* d_out, int out_size, void* d_ws, size_t ws_size,
                              hipStream_t stream) {
  const float* x      = (const float*)d_in[0];
  const float* gate_w = (const float*)d_in[1];
  const float* gate_b = (const float*)d_in[2];
  const float* w1     = (const float*)d_in[3];
  const float* b1     = (const float*)d_in[4];
  const float* w2     = (const float*)d_in[5];
  const float* b2     = (const float*)d_in[6];
  const float* w3     = (const float*)d_in[7];
  const float* b3     = (const float*)d_in[8];
  float* out = (float*)d_out;

  if (ws_size < WS_BASE) {
    fprintf(stderr, "kernel_launch: ws_size %zu < needed %zu\n", ws_size, WS_BASE);
    return;
  }
  const bool store_path = (ws_size >= WS_FULL);

  char* ws = (char*)d_ws;
  unsigned short* xb   = (unsigned short*)(ws + OFF_XB);
  unsigned short* w1bt = (unsigned short*)(ws + OFF_W1);
  unsigned short* w2bt = (unsigned short*)(ws + OFF_W2);
  unsigned short* w3bt = (unsigned short*)(ws + OFF_W3);
  unsigned short* act  = (unsigned short*)(ws + OFF_ACT);
  float* scores        = (float*)(ws + OFF_SC);
  int* route_e         = (int*)(ws + OFF_RE);
  float* route_w       = (float*)(ws + OFF_RW);
  int* tok_list        = (int*)(ws + OFF_TL);
  float* pair_w        = (float*)(ws + OFF_PW);
  int* pair_pos        = (int*)(ws + OFF_PP);
  int* ctrl            = (int*)(ws + OFF_CT);
  unsigned short* pout = (unsigned short*)(ws + OFF_PO);

  if (!store_path)
    hipMemsetAsync(d_out, 0, (size_t)out_size * sizeof(float), stream);

  prep_kernel<<<dim3(2048, 24), 256, 0, stream>>>(w1, w2, w3, w1bt, w2bt, w3bt);
  gate_kernel<<<2048, 256, 0, stream>>>(x, gate_w, gate_b, xb, scores, route_e,
                                        route_w);
  finalize_kernel<<<1, 1024, 0, stream>>>(scores, route_e, ctrl, out + (out_size - 1));
  scatter_kernel<<<32, 256, 0, stream>>>(route_e, route_w, ctrl, tok_list, pair_w,
                                         pair_pos);
  stage1_kernel<<<dim3(16, 32, 8), 512, 0, stream>>>(xb, w1bt, w2bt, b1, b2,
                                                     tok_list, ctrl, act);
  if (store_path) {
    stage2s_kernel<<<dim3(4, 32, 8), 512, 0, stream>>>(act, w3bt, b3, pair_w, ctrl, pout);
    combine_kernel<<<NTOK, 256, 0, stream>>>(pout, pair_pos, out);
  } else {
    stage2a_kernel<<<dim3(4, 32, 8), 512, 0, stream>>>(act, w3bt, b3, tok_list,
                                                       pair_w, ctrl, out);
  }
}

// Round 5
// 567.974 us; speedup vs baseline: 1.4254x; 1.1284x over previous
//
#include <hip/hip_runtime.h>
#include <cstdio>

#define NTOK 8192
#define DIM 1024
#define HID 2048
#define NE 8
#define NPAIR (NTOK * 2)

typedef __attribute__((ext_vector_type(8))) short bf16x8;
typedef __attribute__((ext_vector_type(4))) float f32x4;

typedef const __attribute__((address_space(1))) void* gas_ptr;
typedef __attribute__((address_space(3))) void* las_ptr;

__device__ __forceinline__ void async16(const void* g, void* s) {
  // direct global->LDS, 16B per lane; LDS dest = wave-uniform base + lane*16
  __builtin_amdgcn_global_load_lds((gas_ptr)g, (las_ptr)s, 16, 0, 0);
}

__device__ __forceinline__ unsigned short f2bf(float f) {
  unsigned int u = __float_as_uint(f);
  u = (u + 0x7fff + ((u >> 16) & 1)) >> 16;  // RNE
  return (unsigned short)u;
}

__device__ __forceinline__ float bf2f(unsigned short u) {
  return __uint_as_float((unsigned int)u << 16);
}

// r10: non-GEMM pass. (1) prep: 64x64 tiles, float4 reads, transpose on LDS
// store (stride-65 b32, 2-way alias = free), ushort4 stores — was scalar
// 2B stores + 4KB tiles. (2) scatter: per-block LDS hist -> 8 global atomics
// per block (was 16384 contended). (3) T1 XCD-chunked swizzle on stage1/2:
// one expert per XCD -> shared panels L2-local. GEMM inner loops unchanged
// from r9 (counted-vmcnt 4-deep pipeline, 694 TF).

#define S_BARRIER __builtin_amdgcn_s_barrier()
#define VM_WAIT(N) asm volatile("s_waitcnt vmcnt(" #N ")" ::: "memory")
#define LGKM0 asm volatile("s_waitcnt lgkmcnt(0)" ::: "memory")
#define CFENCE asm volatile("" ::: "memory")

// ---------------------------------------------------------------------------
// prep: w1[e][d][h] -> w1bt[e][h][d] (bf16), w2 same, w3[e][h][d] -> w3bt[e][d][h]
// 64x64 tile per block, 256 thr. tT[c][r] stride 65 -> all LDS b32 ops
// 2-way-bank-alias max. grid (512, 24).
// ---------------------------------------------------------------------------
__global__ __launch_bounds__(256) void prep_kernel(
    const float* __restrict__ w1, const float* __restrict__ w2,
    const float* __restrict__ w3, unsigned short* __restrict__ w1bt,
    unsigned short* __restrict__ w2bt, unsigned short* __restrict__ w3bt) {
  const int z = blockIdx.y;
  const int m = z >> 3, e = z & 7;
  int R, C;
  const float* in;
  unsigned short* outp;
  if (m == 0)      { R = DIM; C = HID; in = w1; outp = w1bt; }
  else if (m == 1) { R = DIM; C = HID; in = w2; outp = w2bt; }
  else             { R = HID; C = DIM; in = w3; outp = w3bt; }
  in += (size_t)e * DIM * HID;
  outp += (size_t)e * DIM * HID;

  const int tilesx = C >> 6;
  const int c0 = (blockIdx.x % tilesx) * 64;
  const int r0 = (blockIdx.x / tilesx) * 64;

  __shared__ float tT[64][65];  // transposed: tT[c][r] = in[r0+r][c0+c]
  const int tid = threadIdx.x;
  const int cq = tid & 15;   // float4-col index
  const int rr = tid >> 4;   // 0..15

#pragma unroll
  for (int p = 0; p < 4; p++) {
    const int r = rr + p * 16;
    const float4 v = *(const float4*)(in + (size_t)(r0 + r) * C + c0 + cq * 4);
    tT[cq * 4 + 0][r] = v.x;
    tT[cq * 4 + 1][r] = v.y;
    tT[cq * 4 + 2][r] = v.z;
    tT[cq * 4 + 3][r] = v.w;
  }
  __syncthreads();
#pragma unroll
  for (int p = 0; p < 4; p++) {
    const int cc = rr + p * 16;
    ushort4 o;
    o.x = f2bf(tT[cc][cq * 4 + 0]);
    o.y = f2bf(tT[cc][cq * 4 + 1]);
    o.z = f2bf(tT[cc][cq * 4 + 2]);
    o.w = f2bf(tT[cc][cq * 4 + 3]);
    *(ushort4*)(outp + (size_t)(c0 + cc) * R + r0 + cq * 4) = o;
  }
}

// ---------------------------------------------------------------------------
// gating: 1 wave per token. Transposed gate_w in LDS -> conflict-free b128
// reads. No atomics here (counts in finalize).
// ---------------------------------------------------------------------------
__global__ __launch_bounds__(256) void gate_kernel(
    const float* __restrict__ x, const float* __restrict__ gw,
    const float* __restrict__ gb, unsigned short* __restrict__ xb,
    float* __restrict__ scores, int* __restrict__ route_e,
    float* __restrict__ route_w) {
  __shared__ float sgwT[NE][DIM];  // 32 KB, transposed [e][d]
  const int tid = threadIdx.x;
#pragma unroll
  for (int i = 0; i < 8; i++) {
    const int j = i * 256 + tid;               // float4 index into gw[DIM][NE]
    const float4 v = ((const float4*)gw)[j];
    const int d = j >> 1, e0 = (j & 1) * 4;    // 2-way bank alias on store: free
    sgwT[e0 + 0][d] = v.x; sgwT[e0 + 1][d] = v.y;
    sgwT[e0 + 2][d] = v.z; sgwT[e0 + 3][d] = v.w;
  }
  __syncthreads();

  const int wv = tid >> 6, lane = tid & 63;
  const int t = blockIdx.x * 4 + wv;
  float acc[NE] = {0.f, 0.f, 0.f, 0.f, 0.f, 0.f, 0.f, 0.f};
  const float4* x4 = (const float4*)(x + (size_t)t * DIM);
#pragma unroll
  for (int i = 0; i < 4; i++) {
    const float4 xv = x4[i * 64 + lane];
    const int d4 = i * 64 + lane;              // float4 index; byte addr lane*16
    ushort4 xbv;
    xbv.x = f2bf(xv.x); xbv.y = f2bf(xv.y);
    xbv.z = f2bf(xv.z); xbv.w = f2bf(xv.w);
    *(ushort4*)(xb + (size_t)t * DIM + d4 * 4) = xbv;
#pragma unroll
    for (int e = 0; e < NE; e++) {
      const float4 wv4 = *(const float4*)&sgwT[e][d4 * 4];  // ds_read_b128, no conflict
      acc[e] += xv.x * wv4.x + xv.y * wv4.y + xv.z * wv4.z + xv.w * wv4.w;
    }
  }
#pragma unroll
  for (int e = 0; e < NE; e++)
#pragma unroll
    for (int s = 32; s; s >>= 1) acc[e] += __shfl_xor(acc[e], s, 64);

  if (lane == 0) {
    float l[NE], m = -1e30f;
#pragma unroll
    for (int e = 0; e < NE; e++) { l[e] = acc[e] + gb[e]; m = fmaxf(m, l[e]); }
    float p[NE], sum = 0.f;
#pragma unroll
    for (int e = 0; e < NE; e++) { p[e] = __expf(l[e] - m); sum += p[e]; }
    const float inv = 1.f / sum;
    float s[NE];
#pragma unroll
    for (int e = 0; e < NE; e++) { s[e] = p[e] * inv; scores[t * NE + e] = s[e]; }
    int i1 = 0;
    for (int e = 1; e < NE; e++) if (s[e] > s[i1]) i1 = e;
    int i2 = -1;
    for (int e = 0; e < NE; e++) {
      if (e == i1) continue;
      if (i2 < 0 || s[e] > s[i2]) i2 = e;
    }
    route_e[t * 2] = i1; route_e[t * 2 + 1] = i2;
    route_w[t * 2] = s[i1]; route_w[t * 2 + 1] = s[i2];
  }
}

// ---------------------------------------------------------------------------
// finalize: usage -> lb_loss (d_out tail); counts via route_e histogram;
// prefix offsets; cursors. Writes every ctrl field (no memset needed).
// ---------------------------------------------------------------------------
__global__ void finalize_kernel(const float* __restrict__ scores,
                                const int* __restrict__ route_e,
                                int* __restrict__ ctrl,
                                float* __restrict__ out_lb) {
  __shared__ float red[1024];
  __shared__ int hist[NE];
  const int tid = threadIdx.x;
  if (tid < NE) hist[tid] = 0;
  const int e = tid & 7, row = tid >> 3;
  float s = 0.f;
  for (int i = 0; i < 64; i++) s += scores[(size_t)(row + i * 128) * NE + e];
  red[tid] = s;
  __syncthreads();  // hist zero + red visible
#pragma unroll
  for (int i = 0; i < 16; i++)
    atomicAdd(&hist[route_e[i * 1024 + tid]], 1);
  for (int st = 512; st >= 8; st >>= 1) {
    __syncthreads();
    if (tid < st) red[tid] += red[tid + st];
  }
  __syncthreads();
  if (tid == 0) {
    float lb = 0.f;
    for (int ee = 0; ee < NE; ee++) {
      const float u = red[ee] * (1.f / 8192.f);
      lb -= u * __logf(u + 1e-9f);
    }
    *out_lb = lb;
    int o = 0;
    for (int ee = 0; ee < NE; ee++) {
      ctrl[ee] = hist[ee];    // counts
      ctrl[8 + ee] = o;       // offsets
      ctrl[17 + ee] = o;      // cursors
      o += hist[ee];
    }
    ctrl[16] = o;
  }
}

// ---------------------------------------------------------------------------
// scatter: per-block LDS histogram -> 8 global atomics per block (was 16384
// contended on 8 addresses). Order within expert list arbitrary (unchanged).
// ---------------------------------------------------------------------------
__global__ __launch_bounds__(256) void scatter_kernel(
    const int* __restrict__ route_e, const float* __restrict__ route_w,
    int* __restrict__ ctrl, int* __restrict__ tok_list,
    float* __restrict__ pair_w, int* __restrict__ pair_pos) {
  __shared__ int lh[NE];
  __shared__ int lbase[NE];
  const int tid = threadIdx.x;
  const int t = blockIdx.x * 256 + tid;
  if (tid < NE) lh[tid] = 0;
  __syncthreads();
  const int e0 = route_e[t * 2], e1 = route_e[t * 2 + 1];
  const int p0 = atomicAdd(&lh[e0], 1);
  const int p1 = atomicAdd(&lh[e1], 1);  // e1 != e0 (top-2 distinct)
  __syncthreads();
  if (tid < NE) lbase[tid] = atomicAdd(&ctrl[17 + tid], lh[tid]);
  __syncthreads();
  const int q0 = lbase[e0] + p0;
  const int q1 = lbase[e1] + p1;
  tok_list[q0] = t;
  pair_w[q0] = route_w[t * 2] * 0.70710678118654752f;
  pair_pos[t * 2] = q0;
  tok_list[q1] = t;
  pair_w[q1] = route_w[t * 2 + 1] * 0.70710678118654752f;
  pair_pos[t * 2 + 1] = q1;
}

// ---------------------------------------------------------------------------
// stage1 (FUSED): act = (X@W1+b1) * silu(X@W2+b2) for routed rows (bf16)
// 1-D grid 4096, block 512, XCD-chunked swizzle (512 blocks = 1 expert/XCD).
// M=256 x N=128 tile, BK=32, 4-deep counted-vmcnt pipeline.
// ---------------------------------------------------------------------------
__global__ __launch_bounds__(512) void stage1_kernel(
    const unsigned short* __restrict__ xb, const unsigned short* __restrict__ w1bt,
    const unsigned short* __restrict__ w2bt, const float* __restrict__ b1,
    const float* __restrict__ b2, const int* __restrict__ tok_list,
    const int* __restrict__ ctrl, unsigned short* __restrict__ act) {
  // bijective chunked swizzle: HW round-robins blockIdx%8 across XCDs ->
  // lid chunks of 512 land on one XCD = exactly one expert.
  const int hbid = blockIdx.x;
  const int lid = ((hbid & 7) << 9) + (hbid >> 3);
  const int e = lid >> 9;
  const int ytile = (lid >> 4) & 31;
  const int h0 = (lid & 15) * 128;

  const int cnt = ctrl[e];
  if (ytile * 256 >= cnt) return;
  const int off = ctrl[8 + e];
  const int rows = min(256, cnt - ytile * 256);

  __shared__ unsigned short sX[4][256 * 32];   // 64 KB
  __shared__ unsigned short sW1[4][128 * 32];  // 32 KB
  __shared__ unsigned short sW2[4][128 * 32];  // 32 KB

  const int tid = threadIdx.x;
  const int wv = tid >> 6, lane = tid & 63;

  // staging: 16B chunk = 8 shorts; 4 chunks/row (BK=32).
  // logical k-chunk of (row, phys p) = p ^ ((row>>1)&3).
  const int cl = ((tid & 3) ^ ((tid >> 3) & 3)) * 8;  // k-offset in shorts

  const unsigned short* w1p = w1bt + (size_t)e * HID * DIM + (size_t)h0 * DIM;
  const unsigned short* w2p = w2bt + (size_t)e * HID * DIM + (size_t)h0 * DIM;
  const unsigned short* gx0 =
      xb + (size_t)tok_list[off + ytile * 256 + min(tid >> 2, rows - 1)] * DIM + cl;
  const unsigned short* gx1 =
      xb + (size_t)tok_list[off + ytile * 256 + min(128 + (tid >> 2), rows - 1)] * DIM + cl;
  const unsigned short* gw1 = w1p + (size_t)(tid >> 2) * DIM + cl;
  const unsigned short* gw2 = w2p + (size_t)(tid >> 2) * DIM + cl;

  f32x4 ah[8][2], ag[8][2];
#pragma unroll
  for (int i = 0; i < 8; i++)
#pragma unroll
    for (int j = 0; j < 2; j++) {
      ah[i][j] = (f32x4){0.f, 0.f, 0.f, 0.f};
      ag[i][j] = (f32x4){0.f, 0.f, 0.f, 0.f};
    }

  const int wr = wv >> 2, wc = wv & 3;
  const int l15 = lane & 15, q = lane >> 4;
  const int pch = (q ^ ((l15 >> 1) & 3)) * 8;

#define S1_STAGE(B)                                   \
  do {                                                \
    async16(gx0, sX[B] + (wv * 64) * 8);              \
    async16(gx1, sX[B] + (512 + wv * 64) * 8);        \
    async16(gw1, sW1[B] + (wv * 64) * 8);             \
    async16(gw2, sW2[B] + (wv * 64) * 8);             \
    gx0 += 32; gx1 += 32; gw1 += 32; gw2 += 32;       \
  } while (0)

  // prologue: stage K0,K1,K2 (12 loads in flight)
  S1_STAGE(0); S1_STAGE(1); S1_STAGE(2);
  VM_WAIT(8);  // K0 landed
  S_BARRIER;
  CFENCE;

  const int NT = DIM / 32;  // 32
  for (int t = 0; t < NT; t++) {
    const int cur = t & 3;
    bf16x8 bx[8], a1[2], a2[2];
    {
      const unsigned short* xs = sX[cur];
      const unsigned short* w1s = sW1[cur];
      const unsigned short* w2s = sW2[cur];
#pragma unroll
      for (int i = 0; i < 8; i++)
        bx[i] = *(const bf16x8*)(xs + (wr * 128 + i * 16 + l15) * 32 + pch);
#pragma unroll
      for (int j = 0; j < 2; j++) {
        a1[j] = *(const bf16x8*)(w1s + (wc * 32 + j * 16 + l15) * 32 + pch);
        a2[j] = *(const bf16x8*)(w2s + (wc * 32 + j * 16 + l15) * 32 + pch);
      }
    }
    if (t < NT - 3) {
      const int nb = (t + 3) & 3;
      S1_STAGE(nb);
    }
    S_BARRIER;
    LGKM0;
    __builtin_amdgcn_sched_barrier(0);
    __builtin_amdgcn_s_setprio(1);
#pragma unroll
    for (int i = 0; i < 8; i++) {
      ah[i][0] = __builtin_amdgcn_mfma_f32_16x16x32_bf16(a1[0], bx[i], ah[i][0], 0, 0, 0);
      ag[i][0] = __builtin_amdgcn_mfma_f32_16x16x32_bf16(a2[0], bx[i], ag[i][0], 0, 0, 0);
      ah[i][1] = __builtin_amdgcn_mfma_f32_16x16x32_bf16(a1[1], bx[i], ah[i][1], 0, 0, 0);
      ag[i][1] = __builtin_amdgcn_mfma_f32_16x16x32_bf16(a2[1], bx[i], ag[i][1], 0, 0, 0);
    }
    __builtin_amdgcn_s_setprio(0);
    if (t < NT - 3) VM_WAIT(8);
    else if (t == NT - 3) VM_WAIT(4);
    else if (t == NT - 2) VM_WAIT(0);
    CFENCE;
    S_BARRIER;
  }
#undef S1_STAGE

  // epilogue: out[token][hcol..hcol+3] = (h+b1) * silu(g+b2), ushort4 stores
  f32x4 b1v[2], b2v[2];
#pragma unroll
  for (int j = 0; j < 2; j++) {
    const int hc = h0 + wc * 32 + j * 16 + q * 4;
    b1v[j] = *(const f32x4*)(b1 + e * HID + hc);
    b2v[j] = *(const f32x4*)(b2 + e * HID + hc);
  }
#pragma unroll
  for (int i = 0; i < 8; i++) {
    const int trow = wr * 128 + i * 16 + l15;
    if (trow < rows) {
      const size_t gp = (size_t)(off + ytile * 256 + trow) * HID;
#pragma unroll
      for (int j = 0; j < 2; j++) {
        const int hc = h0 + wc * 32 + j * 16 + q * 4;
        ushort4 o;
        {
          const float hh = ah[i][j][0] + b1v[j][0];
          const float gg = ag[i][j][0] + b2v[j][0];
          o.x = f2bf(hh * (gg / (1.f + __expf(-gg))));
        }
        {
          const float hh = ah[i][j][1] + b1v[j][1];
          const float gg = ag[i][j][1] + b2v[j][1];
          o.y = f2bf(hh * (gg / (1.f + __expf(-gg))));
        }
        {
          const float hh = ah[i][j][2] + b1v[j][2];
          const float gg = ag[i][j][2] + b2v[j][2];
          o.z = f2bf(hh * (gg / (1.f + __expf(-gg))));
        }
        {
          const float hh = ah[i][j][3] + b1v[j][3];
          const float gg = ag[i][j][3] + b2v[j][3];
          o.w = f2bf(hh * (gg / (1.f + __expf(-gg))));
        }
        *(ushort4*)(act + gp + hc) = o;
      }
    }
  }
}

// ---------------------------------------------------------------------------
// stage2 (store path): pair_out[pr] = (act @ W3 + b3) * wt  (bf16)
// 1-D grid 1024, block 512, XCD-chunked swizzle (128 blocks = 1 expert/XCD).
// 256x256 tile, BK=32, 4-deep pipeline, K=HID.
// ---------------------------------------------------------------------------
__global__ __launch_bounds__(512) void stage2s_kernel(
    const unsigned short* __restrict__ act, const unsigned short* __restrict__ w3bt,
    const float* __restrict__ b3, const float* __restrict__ pair_w,
    const int* __restrict__ ctrl, unsigned short* __restrict__ pair_out) {
  const int hbid = blockIdx.x;
  const int lid = ((hbid & 7) << 7) + (hbid >> 3);
  const int e = lid >> 7;
  const int ytile = (lid >> 2) & 31;
  const int d0 = (lid & 3) * 256;

  const int cnt = ctrl[e];
  if (ytile * 256 >= cnt) return;
  const int off = ctrl[8 + e];
  const int rows = min(256, cnt - ytile * 256);
  const int rbase = off + ytile * 256;

  __shared__ unsigned short sA[4][256 * 32];  // 64 KB
  __shared__ unsigned short sW[4][256 * 32];  // 64 KB

  const int tid = threadIdx.x;
  const int wv = tid >> 6, lane = tid & 63;
  const int cl = ((tid & 3) ^ ((tid >> 3) & 3)) * 8;

  const unsigned short* w3p = w3bt + (size_t)e * DIM * HID + (size_t)d0 * HID;
  const unsigned short* ga0 =
      act + (size_t)(rbase + min(tid >> 2, rows - 1)) * HID + cl;
  const unsigned short* ga1 =
      act + (size_t)(rbase + min(128 + (tid >> 2), rows - 1)) * HID + cl;
  const unsigned short* gw0 = w3p + (size_t)(tid >> 2) * HID + cl;
  const unsigned short* gw1 = w3p + (size_t)(128 + (tid >> 2)) * HID + cl;

  f32x4 acc[8][4];
#pragma unroll
  for (int i = 0; i < 8; i++)
#pragma unroll
    for (int j = 0; j < 4; j++) acc[i][j] = (f32x4){0.f, 0.f, 0.f, 0.f};

  const int wr = wv >> 2, wc = wv & 3;
  const int l15 = lane & 15, q = lane >> 4;
  const int pch = (q ^ ((l15 >> 1) & 3)) * 8;

#define S2_STAGE(B)                                   \
  do {                                                \
    async16(ga0, sA[B] + (wv * 64) * 8);              \
    async16(ga1, sA[B] + (512 + wv * 64) * 8);        \
    async16(gw0, sW[B] + (wv * 64) * 8);              \
    async16(gw1, sW[B] + (512 + wv * 64) * 8);        \
    ga0 += 32; ga1 += 32; gw0 += 32; gw1 += 32;       \
  } while (0)

  S2_STAGE(0); S2_STAGE(1); S2_STAGE(2);
  VM_WAIT(8);
  S_BARRIER;
  CFENCE;

  const int NT = HID / 32;  // 64
  for (int t = 0; t < NT; t++) {
    const int cur = t & 3;
    bf16x8 af[8], bf[4];
    {
      const unsigned short* as = sA[cur];
      const unsigned short* ws = sW[cur];
#pragma unroll
      for (int i = 0; i < 8; i++)
        af[i] = *(const bf16x8*)(as + (wr * 128 + i * 16 + l15) * 32 + pch);
#pragma unroll
      for (int j = 0; j < 4; j++)
        bf[j] = *(const bf16x8*)(ws + (wc * 64 + j * 16 + l15) * 32 + pch);
    }
    if (t < NT - 3) {
      const int nb = (t + 3) & 3;
      S2_STAGE(nb);
    }
    S_BARRIER;
    LGKM0;
    __builtin_amdgcn_sched_barrier(0);
    __builtin_amdgcn_s_setprio(1);
#pragma unroll
    for (int i = 0; i < 8; i++)
#pragma unroll
      for (int j = 0; j < 4; j++)
        acc[i][j] =
            __builtin_amdgcn_mfma_f32_16x16x32_bf16(af[i], bf[j], acc[i][j], 0, 0, 0);
    __builtin_amdgcn_s_setprio(0);
    if (t < NT - 3) VM_WAIT(8);
    else if (t == NT - 3) VM_WAIT(4);
    else if (t == NT - 2) VM_WAIT(0);
    CFENCE;
    S_BARRIER;
  }
#undef S2_STAGE

#pragma unroll
  for (int i = 0; i < 8; i++)
#pragma unroll
    for (int rg = 0; rg < 4; rg++) {
      const int row = wr * 128 + i * 16 + q * 4 + rg;
      if (row < rows) {
        const int pr = rbase + row;
        const float wt = pair_w[pr];
#pragma unroll
        for (int j = 0; j < 4; j++) {
          const int dcol = d0 + wc * 64 + j * 16 + l15;
          pair_out[(size_t)pr * DIM + dcol] = f2bf((acc[i][j][rg] + b3[e * DIM + dcol]) * wt);
        }
      }
    }
}

// ---------------------------------------------------------------------------
// stage2 (atomic fallback): out[tok] += (act @ W3 + b3) * wt
// ---------------------------------------------------------------------------
__global__ __launch_bounds__(512) void stage2a_kernel(
    const unsigned short* __restrict__ act, const unsigned short* __restrict__ w3bt,
    const float* __restrict__ b3, const int* __restrict__ tok_list,
    const float* __restrict__ pair_w, const int* __restrict__ ctrl,
    float* __restrict__ out) {
  const int hbid = blockIdx.x;
  const int lid = ((hbid & 7) << 7) + (hbid >> 3);
  const int e = lid >> 7;
  const int ytile = (lid >> 2) & 31;
  const int d0 = (lid & 3) * 256;

  const int cnt = ctrl[e];
  if (ytile * 256 >= cnt) return;
  const int off = ctrl[8 + e];
  const int rows = min(256, cnt - ytile * 256);
  const int rbase = off + ytile * 256;

  __shared__ unsigned short sA[4][256 * 32];
  __shared__ unsigned short sW[4][256 * 32];

  const int tid = threadIdx.x;
  const int wv = tid >> 6, lane = tid & 63;
  const int cl = ((tid & 3) ^ ((tid >> 3) & 3)) * 8;

  const unsigned short* w3p = w3bt + (size_t)e * DIM * HID + (size_t)d0 * HID;
  const unsigned short* ga0 =
      act + (size_t)(rbase + min(tid >> 2, rows - 1)) * HID + cl;
  const unsigned short* ga1 =
      act + (size_t)(rbase + min(128 + (tid >> 2), rows - 1)) * HID + cl;
  const unsigned short* gw0 = w3p + (size_t)(tid >> 2) * HID + cl;
  const unsigned short* gw1 = w3p + (size_t)(128 + (tid >> 2)) * HID + cl;

  f32x4 acc[8][4];
#pragma unroll
  for (int i = 0; i < 8; i++)
#pragma unroll
    for (int j = 0; j < 4; j++) acc[i][j] = (f32x4){0.f, 0.f, 0.f, 0.f};

  const int wr = wv >> 2, wc = wv & 3;
  const int l15 = lane & 15, q = lane >> 4;
  const int pch = (q ^ ((l15 >> 1) & 3)) * 8;

#define S2A_STAGE(B)                                  \
  do {                                                \
    async16(ga0, sA[B] + (wv * 64) * 8);              \
    async16(ga1, sA[B] + (512 + wv * 64) * 8);        \
    async16(gw0, sW[B] + (wv * 64) * 8);              \
    async16(gw1, sW[B] + (512 + wv * 64) * 8);        \
    ga0 += 32; ga1 += 32; gw0 += 32; gw1 += 32;       \
  } while (0)

  S2A_STAGE(0); S2A_STAGE(1); S2A_STAGE(2);
  VM_WAIT(8);
  S_BARRIER;
  CFENCE;

  const int NT = HID / 32;
  for (int t = 0; t < NT; t++) {
    const int cur = t & 3;
    bf16x8 af[8], bf[4];
    {
      const unsigned short* as = sA[cur];
      const unsigned short* ws = sW[cur];
#pragma unroll
      for (int i = 0; i < 8; i++)
        af[i] = *(const bf16x8*)(as + (wr * 128 + i * 16 + l15) * 32 + pch);
#pragma unroll
      for (int j = 0; j < 4; j++)
        bf[j] = *(const bf16x8*)(ws + (wc * 64 + j * 16 + l15) * 32 + pch);
    }
    if (t < NT - 3) {
      const int nb = (t + 3) & 3;
      S2A_STAGE(nb);
    }
    S_BARRIER;
    LGKM0;
    __builtin_amdgcn_sched_barrier(0);
    __builtin_amdgcn_s_setprio(1);
#pragma unroll
    for (int i = 0; i < 8; i++)
#pragma unroll
      for (int j = 0; j < 4; j++)
        acc[i][j] =
            __builtin_amdgcn_mfma_f32_16x16x32_bf16(af[i], bf[j], acc[i][j], 0, 0, 0);
    __builtin_amdgcn_s_setprio(0);
    if (t < NT - 3) VM_WAIT(8);
    else if (t == NT - 3) VM_WAIT(4);
    else if (t == NT - 2) VM_WAIT(0);
    CFENCE;
    S_BARRIER;
  }
#undef S2A_STAGE

#pragma unroll
  for (int i = 0; i < 8; i++)
#pragma unroll
    for (int rg = 0; rg < 4; rg++) {
      const int row = wr * 128 + i * 16 + q * 4 + rg;
      if (row < rows) {
        const int pr = rbase + row;
        const int tok = tok_list[pr];
        const float wt = pair_w[pr];
#pragma unroll
        for (int j = 0; j < 4; j++) {
          const int dcol = d0 + wc * 64 + j * 16 + l15;
          atomicAdd(out + (size_t)tok * DIM + dcol, (acc[i][j][rg] + b3[e * DIM + dcol]) * wt);
        }
      }
    }
}

// ---------------------------------------------------------------------------
// combine: out[t] = pair_out[pos(t,0)] + pair_out[pos(t,1)]. grid NTOK x 256.
// ---------------------------------------------------------------------------
__global__ __launch_bounds__(256) void combine_kernel(
    const unsigned short* __restrict__ pair_out, const int* __restrict__ pair_pos,
    float* __restrict__ out) {
  const int t = blockIdx.x;
  const int d = threadIdx.x * 4;
  const int p0 = pair_pos[t * 2], p1 = pair_pos[t * 2 + 1];
  const ushort4 a = *(const ushort4*)(pair_out + (size_t)p0 * DIM + d);
  const ushort4 b = *(const ushort4*)(pair_out + (size_t)p1 * DIM + d);
  float4 r;
  r.x = bf2f(a.x) + bf2f(b.x);
  r.y = bf2f(a.y) + bf2f(b.y);
  r.z = bf2f(a.z) + bf2f(b.z);
  r.w = bf2f(a.w) + bf2f(b.w);
  *(float4*)(out + (size_t)t * DIM + d) = r;
}

// ---------------------------------------------------------------------------
// workspace layout (bytes)
// ---------------------------------------------------------------------------
static const size_t SZ_XB  = (size_t)NTOK * DIM * 2;        // 16 MB
static const size_t SZ_W   = (size_t)NE * DIM * HID * 2;    // 32 MB each
static const size_t SZ_ACT = (size_t)NPAIR * HID * 2;       // 64 MB
static const size_t OFF_XB  = 0;
static const size_t OFF_W1  = OFF_XB + SZ_XB;
static const size_t OFF_W2  = OFF_W1 + SZ_W;
static const size_t OFF_W3  = OFF_W2 + SZ_W;
static const size_t OFF_ACT = OFF_W3 + SZ_W;
static const size_t OFF_SC  = OFF_ACT + SZ_ACT;
static const size_t OFF_RE  = OFF_SC + (size_t)NTOK * NE * 4;
static const size_t OFF_RW  = OFF_RE + (size_t)NPAIR * 4;
static const size_t OFF_TL  = OFF_RW + (size_t)NPAIR * 4;
static const size_t OFF_PW  = OFF_TL + (size_t)NPAIR * 4;
static const size_t OFF_PP  = OFF_PW + (size_t)NPAIR * 4;
static const size_t OFF_CT  = OFF_PP + (size_t)NPAIR * 4;
static const size_t WS_BASE = OFF_CT + 128;
static const size_t OFF_PO  = WS_BASE;                      // pair_out bf16, 32 MB
static const size_t WS_FULL = OFF_PO + (size_t)NPAIR * DIM * 2;

extern "C" void kernel_launch(void* const* d_in, const int* in_sizes, int n_in,
                              void* d_out, int out_size, void* d_ws, size_t ws_size,
                              hipStream_t stream) {
  const float* x      = (const float*)d_in[0];
  const float* gate_w = (const float*)d_in[1];
  const float* gate_b = (const float*)d_in[2];
  const float* w1     = (const float*)d_in[3];
  const float* b1     = (const float*)d_in[4];
  const float* w2     = (const float*)d_in[5];
  const float* b2     = (const float*)d_in[6];
  const float* w3     = (const float*)d_in[7];
  const float* b3     = (const float*)d_in[8];
  float* out = (float*)d_out;

  if (ws_size < WS_BASE) {
    fprintf(stderr, "kernel_launch: ws_size %zu < needed %zu\n", ws_size, WS_BASE);
    return;
  }
  const bool store_path = (ws_size >= WS_FULL);

  char* ws = (char*)d_ws;
  unsigned short* xb   = (unsigned short*)(ws + OFF_XB);
  unsigned short* w1bt = (unsigned short*)(ws + OFF_W1);
  unsigned short* w2bt = (unsigned short*)(ws + OFF_W2);
  unsigned short* w3bt = (unsigned short*)(ws + OFF_W3);
  unsigned short* act  = (unsigned short*)(ws + OFF_ACT);
  float* scores        = (float*)(ws + OFF_SC);
  int* route_e         = (int*)(ws + OFF_RE);
  float* route_w       = (float*)(ws + OFF_RW);
  int* tok_list        = (int*)(ws + OFF_TL);
  float* pair_w        = (float*)(ws + OFF_PW);
  int* pair_pos        = (int*)(ws + OFF_PP);
  int* ctrl            = (int*)(ws + OFF_CT);
  unsigned short* pout = (unsigned short*)(ws + OFF_PO);

  if (!store_path)
    hipMemsetAsync(d_out, 0, (size_t)out_size * sizeof(float), stream);

  prep_kernel<<<dim3(512, 24), 256, 0, stream>>>(w1, w2, w3, w1bt, w2bt, w3bt);
  gate_kernel<<<2048, 256, 0, stream>>>(x, gate_w, gate_b, xb, scores, route_e,
                                        route_w);
  finalize_kernel<<<1, 1024, 0, stream>>>(scores, route_e, ctrl, out + (out_size - 1));
  scatter_kernel<<<32, 256, 0, stream>>>(route_e, route_w, ctrl, tok_list, pair_w,
                                         pair_pos);
  stage1_kernel<<<4096, 512, 0, stream>>>(xb, w1bt, w2bt, b1, b2, tok_list, ctrl, act);
  if (store_path) {
    stage2s_kernel<<<1024, 512, 0, stream>>>(act, w3bt, b3, pair_w, ctrl, pout);
    combine_kernel<<<NTOK, 256, 0, stream>>>(pout, pair_pos, out);
  } else {
    stage2a_kernel<<<1024, 512, 0, stream>>>(act, w3bt, b3, tok_list, pair_w,
                                             ctrl, out);
  }
}

// Round 6
// 543.976 us; speedup vs baseline: 1.4883x; 1.0441x over previous
//
#include <hip/hip_runtime.h>
#include <cstdio>

#define NTOK 8192
#define DIM 1024
#define HID 2048
#define NE 8
#define NPAIR (NTOK * 2)

typedef __attribute__((ext_vector_type(8))) short bf16x8;
typedef __attribute__((ext_vector_type(4))) float f32x4;

typedef const __attribute__((address_space(1))) void* gas_ptr;
typedef __attribute__((address_space(3))) void* las_ptr;

__device__ __forceinline__ void async16(const void* g, void* s) {
  // direct global->LDS, 16B per lane; LDS dest = wave-uniform base + lane*16
  __builtin_amdgcn_global_load_lds((gas_ptr)g, (las_ptr)s, 16, 0, 0);
}

__device__ __forceinline__ unsigned short f2bf(float f) {
  unsigned int u = __float_as_uint(f);
  u = (u + 0x7fff + ((u >> 16) & 1)) >> 16;  // RNE
  return (unsigned short)u;
}

__device__ __forceinline__ float bf2f(unsigned short u) {
  return __uint_as_float((unsigned int)u << 16);
}

// r11: (1) de-pinned GEMM inner loop — removed mid-iteration barrier +
// pre-MFMA lgkmcnt(0)+sched_barrier that forced ALL ds_reads to drain before
// ANY MFMA. Compiler now emits fine-grained lgkmcnt(N) so MFMAs start when
// their frags land (m97 asm evidence). End-of-iteration LGKM0+sched_barrier
// remains: guarantees ds_reads of buf[cur] complete before next iteration's
// staging overwrites it, and pins register-only MFMAs from sinking past the
// barrier (rule-18 sink hazard). Counted-vmcnt ledger unchanged (vmcnt(8)
// steady, 4 buffers, 3 tiles in flight). (2) prep+gate fused into one launch
// (independent work overlapped, one less gap).

#define S_BARRIER __builtin_amdgcn_s_barrier()
#define VM_WAIT(N) asm volatile("s_waitcnt vmcnt(" #N ")" ::: "memory")
#define LGKM0 asm volatile("s_waitcnt lgkmcnt(0)" ::: "memory")
#define CFENCE asm volatile("" ::: "memory")

// ---------------------------------------------------------------------------
// prepgate: fused prep (blocks 0..12287) + gate (blocks 12288..14335).
// prep: w1[e][d][h]->w1bt[e][h][d] bf16 (w2 same), w3[e][h][d]->w3bt[e][d][h].
//   64x64 tile, float4 reads, LDS transpose stride 65 (2-way alias = free),
//   ushort4 stores.
// gate: 1 wave/token, transposed gate_w in LDS, conflict-free b128 reads.
// ---------------------------------------------------------------------------
__global__ __launch_bounds__(256) void prepgate_kernel(
    const float* __restrict__ w1, const float* __restrict__ w2,
    const float* __restrict__ w3, unsigned short* __restrict__ w1bt,
    unsigned short* __restrict__ w2bt, unsigned short* __restrict__ w3bt,
    const float* __restrict__ x, const float* __restrict__ gw,
    const float* __restrict__ gb, unsigned short* __restrict__ xb,
    float* __restrict__ scores, int* __restrict__ route_e,
    float* __restrict__ route_w) {
  __shared__ float smem[NE * DIM];  // 32 KB union: prep tT[64][65], gate sgwT
  const int bx = blockIdx.x;
  const int tid = threadIdx.x;

  if (bx < 12288) {
    // ---- prep path ----
    float (*tT)[65] = reinterpret_cast<float(*)[65]>(smem);
    const int z = bx >> 9;     // 0..23
    const int bxx = bx & 511;
    const int m = z >> 3, e = z & 7;
    int R, C;
    const float* in;
    unsigned short* outp;
    if (m == 0)      { R = DIM; C = HID; in = w1; outp = w1bt; }
    else if (m == 1) { R = DIM; C = HID; in = w2; outp = w2bt; }
    else             { R = HID; C = DIM; in = w3; outp = w3bt; }
    in += (size_t)e * DIM * HID;
    outp += (size_t)e * DIM * HID;

    const int tilesx = C >> 6;
    const int c0 = (bxx % tilesx) * 64;
    const int r0 = (bxx / tilesx) * 64;

    const int cq = tid & 15;   // float4-col index
    const int rr = tid >> 4;   // 0..15
#pragma unroll
    for (int p = 0; p < 4; p++) {
      const int r = rr + p * 16;
      const float4 v = *(const float4*)(in + (size_t)(r0 + r) * C + c0 + cq * 4);
      tT[cq * 4 + 0][r] = v.x;
      tT[cq * 4 + 1][r] = v.y;
      tT[cq * 4 + 2][r] = v.z;
      tT[cq * 4 + 3][r] = v.w;
    }
    __syncthreads();
#pragma unroll
    for (int p = 0; p < 4; p++) {
      const int cc = rr + p * 16;
      ushort4 o;
      o.x = f2bf(tT[cc][cq * 4 + 0]);
      o.y = f2bf(tT[cc][cq * 4 + 1]);
      o.z = f2bf(tT[cc][cq * 4 + 2]);
      o.w = f2bf(tT[cc][cq * 4 + 3]);
      *(ushort4*)(outp + (size_t)(c0 + cc) * R + r0 + cq * 4) = o;
    }
    return;
  }

  // ---- gate path ----
  float (*sgwT)[DIM] = reinterpret_cast<float(*)[DIM]>(smem);  // [NE][DIM]
  const int g = bx - 12288;
#pragma unroll
  for (int i = 0; i < 8; i++) {
    const int j = i * 256 + tid;               // float4 index into gw[DIM][NE]
    const float4 v = ((const float4*)gw)[j];
    const int d = j >> 1, e0 = (j & 1) * 4;    // 2-way bank alias on store: free
    sgwT[e0 + 0][d] = v.x; sgwT[e0 + 1][d] = v.y;
    sgwT[e0 + 2][d] = v.z; sgwT[e0 + 3][d] = v.w;
  }
  __syncthreads();

  const int wv = tid >> 6, lane = tid & 63;
  const int t = g * 4 + wv;
  float acc[NE] = {0.f, 0.f, 0.f, 0.f, 0.f, 0.f, 0.f, 0.f};
  const float4* x4 = (const float4*)(x + (size_t)t * DIM);
#pragma unroll
  for (int i = 0; i < 4; i++) {
    const float4 xv = x4[i * 64 + lane];
    const int d4 = i * 64 + lane;
    ushort4 xbv;
    xbv.x = f2bf(xv.x); xbv.y = f2bf(xv.y);
    xbv.z = f2bf(xv.z); xbv.w = f2bf(xv.w);
    *(ushort4*)(xb + (size_t)t * DIM + d4 * 4) = xbv;
#pragma unroll
    for (int e = 0; e < NE; e++) {
      const float4 wv4 = *(const float4*)&sgwT[e][d4 * 4];  // ds_read_b128
      acc[e] += xv.x * wv4.x + xv.y * wv4.y + xv.z * wv4.z + xv.w * wv4.w;
    }
  }
#pragma unroll
  for (int e = 0; e < NE; e++)
#pragma unroll
    for (int s = 32; s; s >>= 1) acc[e] += __shfl_xor(acc[e], s, 64);

  if (lane == 0) {
    float l[NE], m = -1e30f;
#pragma unroll
    for (int e = 0; e < NE; e++) { l[e] = acc[e] + gb[e]; m = fmaxf(m, l[e]); }
    float p[NE], sum = 0.f;
#pragma unroll
    for (int e = 0; e < NE; e++) { p[e] = __expf(l[e] - m); sum += p[e]; }
    const float inv = 1.f / sum;
    float s[NE];
#pragma unroll
    for (int e = 0; e < NE; e++) { s[e] = p[e] * inv; scores[t * NE + e] = s[e]; }
    int i1 = 0;
    for (int e = 1; e < NE; e++) if (s[e] > s[i1]) i1 = e;
    int i2 = -1;
    for (int e = 0; e < NE; e++) {
      if (e == i1) continue;
      if (i2 < 0 || s[e] > s[i2]) i2 = e;
    }
    route_e[t * 2] = i1; route_e[t * 2 + 1] = i2;
    route_w[t * 2] = s[i1]; route_w[t * 2 + 1] = s[i2];
  }
}

// ---------------------------------------------------------------------------
// finalize: usage -> lb_loss (d_out tail); counts via route_e histogram;
// prefix offsets; cursors. Writes every ctrl field (no memset needed).
// ---------------------------------------------------------------------------
__global__ void finalize_kernel(const float* __restrict__ scores,
                                const int* __restrict__ route_e,
                                int* __restrict__ ctrl,
                                float* __restrict__ out_lb) {
  __shared__ float red[1024];
  __shared__ int hist[NE];
  const int tid = threadIdx.x;
  if (tid < NE) hist[tid] = 0;
  const int e = tid & 7, row = tid >> 3;
  float s = 0.f;
  for (int i = 0; i < 64; i++) s += scores[(size_t)(row + i * 128) * NE + e];
  red[tid] = s;
  __syncthreads();  // hist zero + red visible
#pragma unroll
  for (int i = 0; i < 16; i++)
    atomicAdd(&hist[route_e[i * 1024 + tid]], 1);
  for (int st = 512; st >= 8; st >>= 1) {
    __syncthreads();
    if (tid < st) red[tid] += red[tid + st];
  }
  __syncthreads();
  if (tid == 0) {
    float lb = 0.f;
    for (int ee = 0; ee < NE; ee++) {
      const float u = red[ee] * (1.f / 8192.f);
      lb -= u * __logf(u + 1e-9f);
    }
    *out_lb = lb;
    int o = 0;
    for (int ee = 0; ee < NE; ee++) {
      ctrl[ee] = hist[ee];    // counts
      ctrl[8 + ee] = o;       // offsets
      ctrl[17 + ee] = o;      // cursors
      o += hist[ee];
    }
    ctrl[16] = o;
  }
}

// ---------------------------------------------------------------------------
// scatter: per-block LDS histogram -> 8 global atomics per block.
// ---------------------------------------------------------------------------
__global__ __launch_bounds__(256) void scatter_kernel(
    const int* __restrict__ route_e, const float* __restrict__ route_w,
    int* __restrict__ ctrl, int* __restrict__ tok_list,
    float* __restrict__ pair_w, int* __restrict__ pair_pos) {
  __shared__ int lh[NE];
  __shared__ int lbase[NE];
  const int tid = threadIdx.x;
  const int t = blockIdx.x * 256 + tid;
  if (tid < NE) lh[tid] = 0;
  __syncthreads();
  const int e0 = route_e[t * 2], e1 = route_e[t * 2 + 1];
  const int p0 = atomicAdd(&lh[e0], 1);
  const int p1 = atomicAdd(&lh[e1], 1);  // e1 != e0 (top-2 distinct)
  __syncthreads();
  if (tid < NE) lbase[tid] = atomicAdd(&ctrl[17 + tid], lh[tid]);
  __syncthreads();
  const int q0 = lbase[e0] + p0;
  const int q1 = lbase[e1] + p1;
  tok_list[q0] = t;
  pair_w[q0] = route_w[t * 2] * 0.70710678118654752f;
  pair_pos[t * 2] = q0;
  tok_list[q1] = t;
  pair_w[q1] = route_w[t * 2 + 1] * 0.70710678118654752f;
  pair_pos[t * 2 + 1] = q1;
}

// ---------------------------------------------------------------------------
// stage1 (FUSED): act = (X@W1+b1) * silu(X@W2+b2) for routed rows (bf16)
// 1-D grid 4096, block 512, XCD-chunked swizzle (512 blocks = 1 expert/XCD).
// M=256 x N=128 tile, BK=32, 4-deep counted-vmcnt pipeline, de-pinned.
// ---------------------------------------------------------------------------
__global__ __launch_bounds__(512) void stage1_kernel(
    const unsigned short* __restrict__ xb, const unsigned short* __restrict__ w1bt,
    const unsigned short* __restrict__ w2bt, const float* __restrict__ b1,
    const float* __restrict__ b2, const int* __restrict__ tok_list,
    const int* __restrict__ ctrl, unsigned short* __restrict__ act) {
  const int hbid = blockIdx.x;
  const int lid = ((hbid & 7) << 9) + (hbid >> 3);
  const int e = lid >> 9;
  const int ytile = (lid >> 4) & 31;
  const int h0 = (lid & 15) * 128;

  const int cnt = ctrl[e];
  if (ytile * 256 >= cnt) return;
  const int off = ctrl[8 + e];
  const int rows = min(256, cnt - ytile * 256);

  __shared__ unsigned short sX[4][256 * 32];   // 64 KB
  __shared__ unsigned short sW1[4][128 * 32];  // 32 KB
  __shared__ unsigned short sW2[4][128 * 32];  // 32 KB

  const int tid = threadIdx.x;
  const int wv = tid >> 6, lane = tid & 63;
  const int cl = ((tid & 3) ^ ((tid >> 3) & 3)) * 8;  // swizzled k-offset

  const unsigned short* w1p = w1bt + (size_t)e * HID * DIM + (size_t)h0 * DIM;
  const unsigned short* w2p = w2bt + (size_t)e * HID * DIM + (size_t)h0 * DIM;
  const unsigned short* gx0 =
      xb + (size_t)tok_list[off + ytile * 256 + min(tid >> 2, rows - 1)] * DIM + cl;
  const unsigned short* gx1 =
      xb + (size_t)tok_list[off + ytile * 256 + min(128 + (tid >> 2), rows - 1)] * DIM + cl;
  const unsigned short* gw1 = w1p + (size_t)(tid >> 2) * DIM + cl;
  const unsigned short* gw2 = w2p + (size_t)(tid >> 2) * DIM + cl;

  f32x4 ah[8][2], ag[8][2];
#pragma unroll
  for (int i = 0; i < 8; i++)
#pragma unroll
    for (int j = 0; j < 2; j++) {
      ah[i][j] = (f32x4){0.f, 0.f, 0.f, 0.f};
      ag[i][j] = (f32x4){0.f, 0.f, 0.f, 0.f};
    }

  const int wr = wv >> 2, wc = wv & 3;
  const int l15 = lane & 15, q = lane >> 4;
  const int pch = (q ^ ((l15 >> 1) & 3)) * 8;

#define S1_STAGE(B)                                   \
  do {                                                \
    async16(gx0, sX[B] + (wv * 64) * 8);              \
    async16(gx1, sX[B] + (512 + wv * 64) * 8);        \
    async16(gw1, sW1[B] + (wv * 64) * 8);             \
    async16(gw2, sW2[B] + (wv * 64) * 8);             \
    gx0 += 32; gx1 += 32; gw1 += 32; gw2 += 32;       \
  } while (0)

  // prologue: stage K0,K1,K2 (12 loads in flight)
  S1_STAGE(0); S1_STAGE(1); S1_STAGE(2);
  VM_WAIT(8);  // K0 landed
  S_BARRIER;
  CFENCE;

  const int NT = DIM / 32;  // 32
  for (int t = 0; t < NT; t++) {
    const int cur = t & 3;
    bf16x8 bx[8], a1[2], a2[2];
    {
      const unsigned short* xs = sX[cur];
      const unsigned short* w1s = sW1[cur];
      const unsigned short* w2s = sW2[cur];
      // W frags first so the first MFMAs' operands land earliest
#pragma unroll
      for (int j = 0; j < 2; j++) {
        a1[j] = *(const bf16x8*)(w1s + (wc * 32 + j * 16 + l15) * 32 + pch);
        a2[j] = *(const bf16x8*)(w2s + (wc * 32 + j * 16 + l15) * 32 + pch);
      }
#pragma unroll
      for (int i = 0; i < 8; i++)
        bx[i] = *(const bf16x8*)(xs + (wr * 128 + i * 16 + l15) * 32 + pch);
    }
    if (t < NT - 3) {
      const int nb = (t + 3) & 3;
      S1_STAGE(nb);
    }
    // de-pinned: compiler interleaves lgkmcnt(N) waits with MFMA issue
    __builtin_amdgcn_s_setprio(1);
#pragma unroll
    for (int i = 0; i < 8; i++) {
      ah[i][0] = __builtin_amdgcn_mfma_f32_16x16x32_bf16(a1[0], bx[i], ah[i][0], 0, 0, 0);
      ag[i][0] = __builtin_amdgcn_mfma_f32_16x16x32_bf16(a2[0], bx[i], ag[i][0], 0, 0, 0);
      ah[i][1] = __builtin_amdgcn_mfma_f32_16x16x32_bf16(a1[1], bx[i], ah[i][1], 0, 0, 0);
      ag[i][1] = __builtin_amdgcn_mfma_f32_16x16x32_bf16(a2[1], bx[i], ag[i][1], 0, 0, 0);
    }
    __builtin_amdgcn_s_setprio(0);
    LGKM0;  // all ds_reads of buf[cur] done before it can be re-staged
    __builtin_amdgcn_sched_barrier(0);  // pin MFMAs from sinking past barrier
    if (t < NT - 3) VM_WAIT(8);
    else if (t == NT - 3) VM_WAIT(4);
    else if (t == NT - 2) VM_WAIT(0);
    CFENCE;
    S_BARRIER;
  }
#undef S1_STAGE

  // epilogue: out[token][hcol..hcol+3] = (h+b1) * silu(g+b2), ushort4 stores
  f32x4 b1v[2], b2v[2];
#pragma unroll
  for (int j = 0; j < 2; j++) {
    const int hc = h0 + wc * 32 + j * 16 + q * 4;
    b1v[j] = *(const f32x4*)(b1 + e * HID + hc);
    b2v[j] = *(const f32x4*)(b2 + e * HID + hc);
  }
#pragma unroll
  for (int i = 0; i < 8; i++) {
    const int trow = wr * 128 + i * 16 + l15;
    if (trow < rows) {
      const size_t gp = (size_t)(off + ytile * 256 + trow) * HID;
#pragma unroll
      for (int j = 0; j < 2; j++) {
        const int hc = h0 + wc * 32 + j * 16 + q * 4;
        ushort4 o;
        {
          const float hh = ah[i][j][0] + b1v[j][0];
          const float gg = ag[i][j][0] + b2v[j][0];
          o.x = f2bf(hh * (gg / (1.f + __expf(-gg))));
        }
        {
          const float hh = ah[i][j][1] + b1v[j][1];
          const float gg = ag[i][j][1] + b2v[j][1];
          o.y = f2bf(hh * (gg / (1.f + __expf(-gg))));
        }
        {
          const float hh = ah[i][j][2] + b1v[j][2];
          const float gg = ag[i][j][2] + b2v[j][2];
          o.z = f2bf(hh * (gg / (1.f + __expf(-gg))));
        }
        {
          const float hh = ah[i][j][3] + b1v[j][3];
          const float gg = ag[i][j][3] + b2v[j][3];
          o.w = f2bf(hh * (gg / (1.f + __expf(-gg))));
        }
        *(ushort4*)(act + gp + hc) = o;
      }
    }
  }
}

// ---------------------------------------------------------------------------
// stage2 (store path): pair_out[pr] = (act @ W3 + b3) * wt  (bf16)
// 1-D grid 1024, block 512, XCD-chunked swizzle. 256x256 tile, BK=32,
// 4-deep pipeline, de-pinned, K=HID.
// ---------------------------------------------------------------------------
__global__ __launch_bounds__(512) void stage2s_kernel(
    const unsigned short* __restrict__ act, const unsigned short* __restrict__ w3bt,
    const float* __restrict__ b3, const float* __restrict__ pair_w,
    const int* __restrict__ ctrl, unsigned short* __restrict__ pair_out) {
  const int hbid = blockIdx.x;
  const int lid = ((hbid & 7) << 7) + (hbid >> 3);
  const int e = lid >> 7;
  const int ytile = (lid >> 2) & 31;
  const int d0 = (lid & 3) * 256;

  const int cnt = ctrl[e];
  if (ytile * 256 >= cnt) return;
  const int off = ctrl[8 + e];
  const int rows = min(256, cnt - ytile * 256);
  const int rbase = off + ytile * 256;

  __shared__ unsigned short sA[4][256 * 32];  // 64 KB
  __shared__ unsigned short sW[4][256 * 32];  // 64 KB

  const int tid = threadIdx.x;
  const int wv = tid >> 6, lane = tid & 63;
  const int cl = ((tid & 3) ^ ((tid >> 3) & 3)) * 8;

  const unsigned short* w3p = w3bt + (size_t)e * DIM * HID + (size_t)d0 * HID;
  const unsigned short* ga0 =
      act + (size_t)(rbase + min(tid >> 2, rows - 1)) * HID + cl;
  const unsigned short* ga1 =
      act + (size_t)(rbase + min(128 + (tid >> 2), rows - 1)) * HID + cl;
  const unsigned short* gw0 = w3p + (size_t)(tid >> 2) * HID + cl;
  const unsigned short* gw1 = w3p + (size_t)(128 + (tid >> 2)) * HID + cl;

  f32x4 acc[8][4];
#pragma unroll
  for (int i = 0; i < 8; i++)
#pragma unroll
    for (int j = 0; j < 4; j++) acc[i][j] = (f32x4){0.f, 0.f, 0.f, 0.f};

  const int wr = wv >> 2, wc = wv & 3;
  const int l15 = lane & 15, q = lane >> 4;
  const int pch = (q ^ ((l15 >> 1) & 3)) * 8;

#define S2_STAGE(B)                                   \
  do {                                                \
    async16(ga0, sA[B] + (wv * 64) * 8);              \
    async16(ga1, sA[B] + (512 + wv * 64) * 8);        \
    async16(gw0, sW[B] + (wv * 64) * 8);              \
    async16(gw1, sW[B] + (512 + wv * 64) * 8);        \
    ga0 += 32; ga1 += 32; gw0 += 32; gw1 += 32;       \
  } while (0)

  S2_STAGE(0); S2_STAGE(1); S2_STAGE(2);
  VM_WAIT(8);
  S_BARRIER;
  CFENCE;

  const int NT = HID / 32;  // 64
  for (int t = 0; t < NT; t++) {
    const int cur = t & 3;
    bf16x8 af[8], bf[4];
    {
      const unsigned short* as = sA[cur];
      const unsigned short* ws = sW[cur];
#pragma unroll
      for (int j = 0; j < 4; j++)
        bf[j] = *(const bf16x8*)(ws + (wc * 64 + j * 16 + l15) * 32 + pch);
#pragma unroll
      for (int i = 0; i < 8; i++)
        af[i] = *(const bf16x8*)(as + (wr * 128 + i * 16 + l15) * 32 + pch);
    }
    if (t < NT - 3) {
      const int nb = (t + 3) & 3;
      S2_STAGE(nb);
    }
    __builtin_amdgcn_s_setprio(1);
#pragma unroll
    for (int i = 0; i < 8; i++)
#pragma unroll
      for (int j = 0; j < 4; j++)
        acc[i][j] =
            __builtin_amdgcn_mfma_f32_16x16x32_bf16(af[i], bf[j], acc[i][j], 0, 0, 0);
    __builtin_amdgcn_s_setprio(0);
    LGKM0;
    __builtin_amdgcn_sched_barrier(0);
    if (t < NT - 3) VM_WAIT(8);
    else if (t == NT - 3) VM_WAIT(4);
    else if (t == NT - 2) VM_WAIT(0);
    CFENCE;
    S_BARRIER;
  }
#undef S2_STAGE

#pragma unroll
  for (int i = 0; i < 8; i++)
#pragma unroll
    for (int rg = 0; rg < 4; rg++) {
      const int row = wr * 128 + i * 16 + q * 4 + rg;
      if (row < rows) {
        const int pr = rbase + row;
        const float wt = pair_w[pr];
#pragma unroll
        for (int j = 0; j < 4; j++) {
          const int dcol = d0 + wc * 64 + j * 16 + l15;
          pair_out[(size_t)pr * DIM + dcol] = f2bf((acc[i][j][rg] + b3[e * DIM + dcol]) * wt);
        }
      }
    }
}

// ---------------------------------------------------------------------------
// stage2 (atomic fallback): out[tok] += (act @ W3 + b3) * wt
// ---------------------------------------------------------------------------
__global__ __launch_bounds__(512) void stage2a_kernel(
    const unsigned short* __restrict__ act, const unsigned short* __restrict__ w3bt,
    const float* __restrict__ b3, const int* __restrict__ tok_list,
    const float* __restrict__ pair_w, const int* __restrict__ ctrl,
    float* __restrict__ out) {
  const int hbid = blockIdx.x;
  const int lid = ((hbid & 7) << 7) + (hbid >> 3);
  const int e = lid >> 7;
  const int ytile = (lid >> 2) & 31;
  const int d0 = (lid & 3) * 256;

  const int cnt = ctrl[e];
  if (ytile * 256 >= cnt) return;
  const int off = ctrl[8 + e];
  const int rows = min(256, cnt - ytile * 256);
  const int rbase = off + ytile * 256;

  __shared__ unsigned short sA[4][256 * 32];
  __shared__ unsigned short sW[4][256 * 32];

  const int tid = threadIdx.x;
  const int wv = tid >> 6, lane = tid & 63;
  const int cl = ((tid & 3) ^ ((tid >> 3) & 3)) * 8;

  const unsigned short* w3p = w3bt + (size_t)e * DIM * HID + (size_t)d0 * HID;
  const unsigned short* ga0 =
      act + (size_t)(rbase + min(tid >> 2, rows - 1)) * HID + cl;
  const unsigned short* ga1 =
      act + (size_t)(rbase + min(128 + (tid >> 2), rows - 1)) * HID + cl;
  const unsigned short* gw0 = w3p + (size_t)(tid >> 2) * HID + cl;
  const unsigned short* gw1 = w3p + (size_t)(128 + (tid >> 2)) * HID + cl;

  f32x4 acc[8][4];
#pragma unroll
  for (int i = 0; i < 8; i++)
#pragma unroll
    for (int j = 0; j < 4; j++) acc[i][j] = (f32x4){0.f, 0.f, 0.f, 0.f};

  const int wr = wv >> 2, wc = wv & 3;
  const int l15 = lane & 15, q = lane >> 4;
  const int pch = (q ^ ((l15 >> 1) & 3)) * 8;

#define S2A_STAGE(B)                                  \
  do {                                                \
    async16(ga0, sA[B] + (wv * 64) * 8);              \
    async16(ga1, sA[B] + (512 + wv * 64) * 8);        \
    async16(gw0, sW[B] + (wv * 64) * 8);              \
    async16(gw1, sW[B] + (512 + wv * 64) * 8);        \
    ga0 += 32; ga1 += 32; gw0 += 32; gw1 += 32;       \
  } while (0)

  S2A_STAGE(0); S2A_STAGE(1); S2A_STAGE(2);
  VM_WAIT(8);
  S_BARRIER;
  CFENCE;

  const int NT = HID / 32;
  for (int t = 0; t < NT; t++) {
    const int cur = t & 3;
    bf16x8 af[8], bf[4];
    {
      const unsigned short* as = sA[cur];
      const unsigned short* ws = sW[cur];
#pragma unroll
      for (int j = 0; j < 4; j++)
        bf[j] = *(const bf16x8*)(ws + (wc * 64 + j * 16 + l15) * 32 + pch);
#pragma unroll
      for (int i = 0; i < 8; i++)
        af[i] = *(const bf16x8*)(as + (wr * 128 + i * 16 + l15) * 32 + pch);
    }
    if (t < NT - 3) {
      const int nb = (t + 3) & 3;
      S2A_STAGE(nb);
    }
    __builtin_amdgcn_s_setprio(1);
#pragma unroll
    for (int i = 0; i < 8; i++)
#pragma unroll
      for (int j = 0; j < 4; j++)
        acc[i][j] =
            __builtin_amdgcn_mfma_f32_16x16x32_bf16(af[i], bf[j], acc[i][j], 0, 0, 0);
    __builtin_amdgcn_s_setprio(0);
    LGKM0;
    __builtin_amdgcn_sched_barrier(0);
    if (t < NT - 3) VM_WAIT(8);
    else if (t == NT - 3) VM_WAIT(4);
    else if (t == NT - 2) VM_WAIT(0);
    CFENCE;
    S_BARRIER;
  }
#undef S2A_STAGE

#pragma unroll
  for (int i = 0; i < 8; i++)
#pragma unroll
    for (int rg = 0; rg < 4; rg++) {
      const int row = wr * 128 + i * 16 + q * 4 + rg;
      if (row < rows) {
        const int pr = rbase + row;
        const int tok = tok_list[pr];
        const float wt = pair_w[pr];
#pragma unroll
        for (int j = 0; j < 4; j++) {
          const int dcol = d0 + wc * 64 + j * 16 + l15;
          atomicAdd(out + (size_t)tok * DIM + dcol, (acc[i][j][rg] + b3[e * DIM + dcol]) * wt);
        }
      }
    }
}

// ---------------------------------------------------------------------------
// combine: out[t] = pair_out[pos(t,0)] + pair_out[pos(t,1)]. grid NTOK x 256.
// ---------------------------------------------------------------------------
__global__ __launch_bounds__(256) void combine_kernel(
    const unsigned short* __restrict__ pair_out, const int* __restrict__ pair_pos,
    float* __restrict__ out) {
  const int t = blockIdx.x;
  const int d = threadIdx.x * 4;
  const int p0 = pair_pos[t * 2], p1 = pair_pos[t * 2 + 1];
  const ushort4 a = *(const ushort4*)(pair_out + (size_t)p0 * DIM + d);
  const ushort4 b = *(const ushort4*)(pair_out + (size_t)p1 * DIM + d);
  float4 r;
  r.x = bf2f(a.x) + bf2f(b.x);
  r.y = bf2f(a.y) + bf2f(b.y);
  r.z = bf2f(a.z) + bf2f(b.z);
  r.w = bf2f(a.w) + bf2f(b.w);
  *(float4*)(out + (size_t)t * DIM + d) = r;
}

// ---------------------------------------------------------------------------
// workspace layout (bytes)
// ---------------------------------------------------------------------------
static const size_t SZ_XB  = (size_t)NTOK * DIM * 2;        // 16 MB
static const size_t SZ_W   = (size_t)NE * DIM * HID * 2;    // 32 MB each
static const size_t SZ_ACT = (size_t)NPAIR * HID * 2;       // 64 MB
static const size_t OFF_XB  = 0;
static const size_t OFF_W1  = OFF_XB + SZ_XB;
static const size_t OFF_W2  = OFF_W1 + SZ_W;
static const size_t OFF_W3  = OFF_W2 + SZ_W;
static const size_t OFF_ACT = OFF_W3 + SZ_W;
static const size_t OFF_SC  = OFF_ACT + SZ_ACT;
static const size_t OFF_RE  = OFF_SC + (size_t)NTOK * NE * 4;
static const size_t OFF_RW  = OFF_RE + (size_t)NPAIR * 4;
static const size_t OFF_TL  = OFF_RW + (size_t)NPAIR * 4;
static const size_t OFF_PW  = OFF_TL + (size_t)NPAIR * 4;
static const size_t OFF_PP  = OFF_PW + (size_t)NPAIR * 4;
static const size_t OFF_CT  = OFF_PP + (size_t)NPAIR * 4;
static const size_t WS_BASE = OFF_CT + 128;
static const size_t OFF_PO  = WS_BASE;                      // pair_out bf16, 32 MB
static const size_t WS_FULL = OFF_PO + (size_t)NPAIR * DIM * 2;

extern "C" void kernel_launch(void* const* d_in, const int* in_sizes, int n_in,
                              void* d_out, int out_size, void* d_ws, size_t ws_size,
                              hipStream_t stream) {
  const float* x      = (const float*)d_in[0];
  const float* gate_w = (const float*)d_in[1];
  const float* gate_b = (const float*)d_in[2];
  const float* w1     = (const float*)d_in[3];
  const float* b1     = (const float*)d_in[4];
  const float* w2     = (const float*)d_in[5];
  const float* b2     = (const float*)d_in[6];
  const float* w3     = (const float*)d_in[7];
  const float* b3     = (const float*)d_in[8];
  float* out = (float*)d_out;

  if (ws_size < WS_BASE) {
    fprintf(stderr, "kernel_launch: ws_size %zu < needed %zu\n", ws_size, WS_BASE);
    return;
  }
  const bool store_path = (ws_size >= WS_FULL);

  char* ws = (char*)d_ws;
  unsigned short* xb   = (unsigned short*)(ws + OFF_XB);
  unsigned short* w1bt = (unsigned short*)(ws + OFF_W1);
  unsigned short* w2bt = (unsigned short*)(ws + OFF_W2);
  unsigned short* w3bt = (unsigned short*)(ws + OFF_W3);
  unsigned short* act  = (unsigned short*)(ws + OFF_ACT);
  float* scores        = (float*)(ws + OFF_SC);
  int* route_e         = (int*)(ws + OFF_RE);
  float* route_w       = (float*)(ws + OFF_RW);
  int* tok_list        = (int*)(ws + OFF_TL);
  float* pair_w        = (float*)(ws + OFF_PW);
  int* pair_pos        = (int*)(ws + OFF_PP);
  int* ctrl            = (int*)(ws + OFF_CT);
  unsigned short* pout = (unsigned short*)(ws + OFF_PO);

  if (!store_path)
    hipMemsetAsync(d_out, 0, (size_t)out_size * sizeof(float), stream);

  prepgate_kernel<<<14336, 256, 0, stream>>>(w1, w2, w3, w1bt, w2bt, w3bt,
                                             x, gate_w, gate_b, xb, scores,
                                             route_e, route_w);
  finalize_kernel<<<1, 1024, 0, stream>>>(scores, route_e, ctrl, out + (out_size - 1));
  scatter_kernel<<<32, 256, 0, stream>>>(route_e, route_w, ctrl, tok_list, pair_w,
                                         pair_pos);
  stage1_kernel<<<4096, 512, 0, stream>>>(xb, w1bt, w2bt, b1, b2, tok_list, ctrl, act);
  if (store_path) {
    stage2s_kernel<<<1024, 512, 0, stream>>>(act, w3bt, b3, pair_w, ctrl, pout);
    combine_kernel<<<NTOK, 256, 0, stream>>>(pout, pair_pos, out);
  } else {
    stage2a_kernel<<<1024, 512, 0, stream>>>(act, w3bt, b3, tok_list, pair_w,
                                             ctrl, out);
  }
}